// Round 12
// baseline (641.792 us; speedup 1.0000x reference)
//
#include <hip/hip_runtime.h>
#include <math.h>

#define QL 2048
#define SL 2048
#define BS 4
#define NH 4
#define FSZ ((size_t)BS * QL * 128)   // 1,048,576 floats = 4 MB

typedef short bf16x8 __attribute__((ext_vector_type(8)));
typedef float f32x4 __attribute__((ext_vector_type(4)));

__device__ __forceinline__ short to_bf16_rne(float x) {
    unsigned u = __float_as_uint(x);
    unsigned r = u + 0x7fffu + ((u >> 16) & 1u);
    return (short)(r >> 16);
}

__device__ __forceinline__ void split8(const float* x, bf16x8& hi, bf16x8& lo) {
    #pragma unroll
    for (int j = 0; j < 8; j++) {
        short hh = to_bf16_rne(x[j]);
        float hf = __uint_as_float(((unsigned)(unsigned short)hh) << 16);
        hi[j] = hh;
        lo[j] = to_bf16_rne(x[j] - hf);
    }
}

// ---------------------------------------------------------------------------
// Projection GEMM via split-bf16 MFMA (validated round 10)
// ---------------------------------------------------------------------------
__global__ __launch_bounds__(256) void proj_mfma_kernel(
    const float* __restrict__ q, const float* __restrict__ k, const float* __restrict__ v,
    const float* __restrict__ Wqa, const float* __restrict__ Wqb,
    const float* __restrict__ Wka, const float* __restrict__ Wkb,
    const float* __restrict__ Wva, const float* __restrict__ Wvb,
    float* __restrict__ ws)
{
    int id = blockIdx.y;
    const float* X; const float* W;
    const size_t HALF = (size_t)BS * QL * 256;
    switch (id) {
      case 0: X = q;        W = Wqa; break;
      case 1: X = q + HALF; W = Wqb; break;
      case 2: X = k;        W = Wka; break;
      case 3: X = k + HALF; W = Wkb; break;
      case 4: X = v;        W = Wva; break;
      default:X = v + HALF; W = Wvb; break;
    }
    float* Y = ws + (size_t)id * FSZ;
    int m0 = blockIdx.x * 128;

    __shared__ short lA[128 * 64];
    __shared__ short lB[128 * 64];

    int t = threadIdx.x;
    int srow = t >> 1, shalf = t & 1;
    int l = t & 63, w = t >> 6;
    int wr = w >> 1, wc = w & 1;
    int lr = l & 15, kb = l >> 4;

    f32x4 acc[4][4] = {};

    for (int kc = 0; kc < 256; kc += 32) {
        {
            const float* srcA = X + (size_t)(m0 + srow) * 256 + kc + shalf * 16;
            float xa[16];
            #pragma unroll
            for (int j = 0; j < 4; j++)
                *(float4*)&xa[j * 4] = *(const float4*)(srcA + j * 4);
            bf16x8 h0, l0, h1, l1;
            split8(&xa[0], h0, l0);
            split8(&xa[8], h1, l1);
            int base = srow * 64, r7 = srow & 7;
            *(bf16x8*)&lA[base + (((4 * shalf + 0) ^ r7) * 8)] = h0;
            *(bf16x8*)&lA[base + (((4 * shalf + 1) ^ r7) * 8)] = l0;
            *(bf16x8*)&lA[base + (((4 * shalf + 2) ^ r7) * 8)] = h1;
            *(bf16x8*)&lA[base + (((4 * shalf + 3) ^ r7) * 8)] = l1;
        }
        {
            int ncol = srow;
            float xb[16];
            #pragma unroll
            for (int j = 0; j < 16; j++)
                xb[j] = W[(size_t)(kc + shalf * 16 + j) * 128 + ncol];
            bf16x8 h0, l0, h1, l1;
            split8(&xb[0], h0, l0);
            split8(&xb[8], h1, l1);
            int base = ncol * 64, r7 = ncol & 7;
            *(bf16x8*)&lB[base + (((4 * shalf + 0) ^ r7) * 8)] = h0;
            *(bf16x8*)&lB[base + (((4 * shalf + 1) ^ r7) * 8)] = l0;
            *(bf16x8*)&lB[base + (((4 * shalf + 2) ^ r7) * 8)] = h1;
            *(bf16x8*)&lB[base + (((4 * shalf + 3) ^ r7) * 8)] = l1;
        }
        __syncthreads();

        bf16x8 ah[4], al[4], bhv[4], blv[4];
        #pragma unroll
        for (int m = 0; m < 4; m++) {
            int r = wr * 64 + m * 16 + lr;
            int r7 = r & 7, base = r * 64;
            ah[m] = *(bf16x8*)&lA[base + (((2 * kb + 0) ^ r7) * 8)];
            al[m] = *(bf16x8*)&lA[base + (((2 * kb + 1) ^ r7) * 8)];
        }
        #pragma unroll
        for (int n = 0; n < 4; n++) {
            int r = wc * 64 + n * 16 + lr;
            int r7 = r & 7, base = r * 64;
            bhv[n] = *(bf16x8*)&lB[base + (((2 * kb + 0) ^ r7) * 8)];
            blv[n] = *(bf16x8*)&lB[base + (((2 * kb + 1) ^ r7) * 8)];
        }
        #pragma unroll
        for (int m = 0; m < 4; m++) {
            #pragma unroll
            for (int n = 0; n < 4; n++) {
                acc[m][n] = __builtin_amdgcn_mfma_f32_16x16x32_bf16(ah[m], bhv[n], acc[m][n], 0, 0, 0);
                acc[m][n] = __builtin_amdgcn_mfma_f32_16x16x32_bf16(ah[m], blv[n], acc[m][n], 0, 0, 0);
                acc[m][n] = __builtin_amdgcn_mfma_f32_16x16x32_bf16(al[m], bhv[n], acc[m][n], 0, 0, 0);
            }
        }
        __syncthreads();
    }

    #pragma unroll
    for (int n = 0; n < 4; n++) {
        int gcol = wc * 64 + n * 16 + lr;
        #pragma unroll
        for (int m = 0; m < 4; m++) {
            int grow = m0 + wr * 64 + m * 16 + kb * 4;
            float* dst = Y + (size_t)grow * 128 + gcol;
            f32x4 c = acc[m][n];
            dst[0 * 128] = c[0];
            dst[1 * 128] = c[1];
            dst[2 * 128] = c[2];
            dst[3 * 128] = c[3];
        }
    }
}

// ---------------------------------------------------------------------------
// Spatial rotation -> split-bf16 pre-swizzled planes; z selects q vs kv.
// ---------------------------------------------------------------------------
__global__ __launch_bounds__(256) void rot_split_kernel(
    const float* __restrict__ qa, const float* __restrict__ qb,
    const float* __restrict__ ka, const float* __restrict__ kb,
    const float* __restrict__ qse, const float* __restrict__ kvse,
    short* __restrict__ qrotS, short* __restrict__ krotS)
{
    int tkn = blockIdx.x;
    int b = blockIdx.y;
    int z = blockIdx.z;                       // 0 = q, 1 = kv
    const float* ha = z ? ka : qa;
    const float* hb = z ? kb : qb;
    const float* E = z ? (kvse + (size_t)(b * SL + tkn) * 16384)
                       : (qse + (size_t)b * 16384);
    short* rotS = z ? krotS : qrotS;

    __shared__ float hv[4][128];
    __shared__ float outl[4][128];
    int tid = threadIdx.x;
    size_t tok = (size_t)(b * QL + tkn) * 128;
    for (int idx = tid; idx < 512; idx += 256) {
        int h = idx >> 7, d = idx & 127;
        float val = (d < 64) ? ha[tok + (h & 1) * 64 + d]
                             : hb[tok + (h >> 1) * 64 + (d - 64)];
        hv[h][d] = val;
    }
    __syncthreads();
    int w = tid >> 6, lane = tid & 63;
    int half = lane >> 5, l5 = lane & 31;
    for (int it = 0; it < 16; ++it) {
        int i = w * 32 + it * 2 + half;
        float4 e = *(const float4*)(E + (size_t)i * 128 + l5 * 4);
        float acc[4];
        #pragma unroll
        for (int h = 0; h < 4; h++) {
            float4 x = *(const float4*)&hv[h][l5 * 4];
            acc[h] = e.x * x.x + e.y * x.y + e.z * x.z + e.w * x.w;
        }
        #pragma unroll
        for (int off = 1; off < 32; off <<= 1) {
            #pragma unroll
            for (int h = 0; h < 4; h++) acc[h] += __shfl_xor(acc[h], off);
        }
        if (l5 < 4) outl[l5][i] = acc[l5];
    }
    __syncthreads();
    if (tid < 128) {
        int h    = tid >> 5;
        int kcid = (tid >> 3) & 3;
        int s    = tid & 7;
        int shalf = s >> 2;
        int isLo  = s & 1;
        int jbase = ((s >> 1) & 1) * 8;
        int dbase = kcid * 32 + shalf * 16 + jbase;
        bf16x8 outv;
        #pragma unroll
        for (int j = 0; j < 8; j++) {
            float x = outl[h][dbase + j];
            short hh = to_bf16_rne(x);
            if (isLo) {
                float hf = __uint_as_float(((unsigned)(unsigned short)hh) << 16);
                outv[j] = to_bf16_rne(x - hf);
            } else {
                outv[j] = hh;
            }
        }
        int bh = b * NH + h;
        int row = tkn & 127;
        size_t base = ((((size_t)bh * 16 + (tkn >> 7)) * 4 + kcid) * 128 + row) * 64;
        *(bf16x8*)&rotS[base + (size_t)((s ^ (row & 7)) * 8)] = outv;
    }
}

// ---------------------------------------------------------------------------
// Score GEMM via split-bf16 MFMA + fused softmax partials.
// S-store routed through LDS (reusing lA/lB space) for 512B-coalesced writes.
// ---------------------------------------------------------------------------
__global__ __launch_bounds__(256) void score_mfma_kernel(
    const short* __restrict__ qrotS, const short* __restrict__ krotS,
    const float* __restrict__ bias, const int* __restrict__ mask,
    float* __restrict__ attn, float* __restrict__ stats)
{
    __shared__ __align__(16) char smemRaw[64 * 132 * 4];   // 33792 B
    short* lA = (short*)smemRaw;                 // 16 KB (MFMA phase)
    short* lB = (short*)(smemRaw + 16384);       // 16 KB (MFMA phase)
    float* sOut = (float*)smemRaw;               // 64x132 floats (store phase)
    __shared__ float redM[128][2];
    __shared__ float redS[128][2];

    int bid = blockIdx.x;                       // 4096
    int wg = (bid & 7) * 512 + (bid >> 3);      // XCD-chunked swizzle
    int bh = wg >> 8;
    int qt = (wg >> 4) & 15, st = wg & 15;
    int q0 = qt * 128, s0 = st * 128;
    int b = bh >> 2;

    int t = threadIdx.x;
    int l = t & 63, w = t >> 6;
    int wr = w >> 1, wc = w & 1;
    int lr = l & 15, kb = l >> 4;

    const short* Abase = qrotS + (((size_t)bh * 16 + qt) * 4) * 8192;
    const short* Bbase = krotS + (((size_t)bh * 16 + st) * 4) * 8192;

    f32x4 acc[4][4] = {};

    for (int kcid = 0; kcid < 4; kcid++) {
        {
            const bf16x8* srcA = (const bf16x8*)(Abase + (size_t)kcid * 8192) + t * 4;
            const bf16x8* srcB = (const bf16x8*)(Bbase + (size_t)kcid * 8192) + t * 4;
            bf16x8 a0 = srcA[0], a1 = srcA[1], a2 = srcA[2], a3 = srcA[3];
            bf16x8 b0 = srcB[0], b1 = srcB[1], b2 = srcB[2], b3 = srcB[3];
            bf16x8* dA = (bf16x8*)lA + t * 4;
            bf16x8* dB = (bf16x8*)lB + t * 4;
            dA[0] = a0; dA[1] = a1; dA[2] = a2; dA[3] = a3;
            dB[0] = b0; dB[1] = b1; dB[2] = b2; dB[3] = b3;
        }
        __syncthreads();

        bf16x8 ah[4], al[4], bhv[4], blv[4];
        #pragma unroll
        for (int m = 0; m < 4; m++) {
            int r = wr * 64 + m * 16 + lr;
            int r7 = r & 7, base = r * 64;
            ah[m] = *(bf16x8*)&lA[base + (((2 * kb + 0) ^ r7) * 8)];
            al[m] = *(bf16x8*)&lA[base + (((2 * kb + 1) ^ r7) * 8)];
        }
        #pragma unroll
        for (int n = 0; n < 4; n++) {
            int r = wc * 64 + n * 16 + lr;
            int r7 = r & 7, base = r * 64;
            bhv[n] = *(bf16x8*)&lB[base + (((2 * kb + 0) ^ r7) * 8)];
            blv[n] = *(bf16x8*)&lB[base + (((2 * kb + 1) ^ r7) * 8)];
        }
        #pragma unroll
        for (int m = 0; m < 4; m++) {
            #pragma unroll
            for (int n = 0; n < 4; n++) {
                acc[m][n] = __builtin_amdgcn_mfma_f32_16x16x32_bf16(ah[m], bhv[n], acc[m][n], 0, 0, 0);
                acc[m][n] = __builtin_amdgcn_mfma_f32_16x16x32_bf16(ah[m], blv[n], acc[m][n], 0, 0, 0);
                acc[m][n] = __builtin_amdgcn_mfma_f32_16x16x32_bf16(al[m], bhv[n], acc[m][n], 0, 0, 0);
            }
        }
        __syncthreads();
    }

    // ---- finalize S in registers (scale + mask/bias) ----
    const float scale = 0.08838834764831845f;   // 1/sqrt(128)
    #pragma unroll
    for (int n = 0; n < 4; n++) {
        int gs = s0 + wc * 64 + n * 16 + lr;
        float adj = -1e9f * (float)mask[b * SL + gs] - bias[b * SL + gs];
        #pragma unroll
        for (int m = 0; m < 4; m++) {
            f32x4 c = acc[m][n];
            c[0] = c[0] * scale + adj;
            c[1] = c[1] * scale + adj;
            c[2] = c[2] * scale + adj;
            c[3] = c[3] * scale + adj;
            acc[m][n] = c;
        }
    }

    // ---- coalesced S store via LDS: two 64-row passes ----
    int lane = t & 63, wv = t >> 6;
    #pragma unroll
    for (int p = 0; p < 2; p++) {
        if (wr == p) {
            #pragma unroll
            for (int m = 0; m < 4; m++) {
                #pragma unroll
                for (int n = 0; n < 4; n++) {
                    int localq = m * 16 + kb * 4;
                    int locals = wc * 64 + n * 16 + lr;
                    f32x4 c = acc[m][n];
                    sOut[(localq + 0) * 132 + locals] = c[0];
                    sOut[(localq + 1) * 132 + locals] = c[1];
                    sOut[(localq + 2) * 132 + locals] = c[2];
                    sOut[(localq + 3) * 132 + locals] = c[3];
                }
            }
        }
        __syncthreads();
        #pragma unroll
        for (int j = 0; j < 8; j++) {
            int row = j * 8 + wv * 2 + (lane >> 5);
            int c4 = (lane & 31) * 4;
            float4 vvv = make_float4(sOut[row * 132 + c4],     sOut[row * 132 + c4 + 1],
                                     sOut[row * 132 + c4 + 2], sOut[row * 132 + c4 + 3]);
            *(float4*)(attn + ((size_t)bh * QL + q0 + p * 64 + row) * SL + s0 + c4) = vvv;
        }
        __syncthreads();
    }

    // ---- per-row tile max ----
    #pragma unroll
    for (int m = 0; m < 4; m++) {
        #pragma unroll
        for (int i = 0; i < 4; i++) {
            float rm = fmaxf(fmaxf(acc[m][0][i], acc[m][1][i]),
                             fmaxf(acc[m][2][i], acc[m][3][i]));
            rm = fmaxf(rm, __shfl_xor(rm, 1));
            rm = fmaxf(rm, __shfl_xor(rm, 2));
            rm = fmaxf(rm, __shfl_xor(rm, 4));
            rm = fmaxf(rm, __shfl_xor(rm, 8));
            if (lr == 0) redM[wr * 64 + m * 16 + kb * 4 + i][wc] = rm;
        }
    }
    __syncthreads();
    // ---- per-row tile expsum relative to combined tile max ----
    #pragma unroll
    for (int m = 0; m < 4; m++) {
        #pragma unroll
        for (int i = 0; i < 4; i++) {
            int row = wr * 64 + m * 16 + kb * 4 + i;
            float mt = fmaxf(redM[row][0], redM[row][1]);
            float es = __expf(acc[m][0][i] - mt) + __expf(acc[m][1][i] - mt)
                     + __expf(acc[m][2][i] - mt) + __expf(acc[m][3][i] - mt);
            es += __shfl_xor(es, 1);
            es += __shfl_xor(es, 2);
            es += __shfl_xor(es, 4);
            es += __shfl_xor(es, 8);
            if (lr == 0) redS[row][wc] = es;
        }
    }
    __syncthreads();
    if (t < 128) {
        float mt = fmaxf(redM[t][0], redM[t][1]);
        float es = redS[t][0] + redS[t][1];
        size_t r = (size_t)bh * QL + q0 + t;
        stats[(r * 16 + st) * 2 + 0] = mt;
        stats[(r * 16 + st) * 2 + 1] = es;
    }
}

// ---------------------------------------------------------------------------
// Flash combine: per row, 16 (max, expsum) partials -> rowmax, 1/rowsum.
// ---------------------------------------------------------------------------
__global__ __launch_bounds__(256) void sreduce_kernel(
    const float* __restrict__ stats,
    float* __restrict__ rowm, float* __restrict__ rowinv)
{
    int r = blockIdx.x * 256 + threadIdx.x;     // 32768 rows
    const float* src = stats + (size_t)r * 32;
    float4 p[8];
    #pragma unroll
    for (int j = 0; j < 8; j++) p[j] = *(const float4*)(src + j * 4);
    float m = -INFINITY;
    #pragma unroll
    for (int j = 0; j < 8; j++) { m = fmaxf(m, p[j].x); m = fmaxf(m, p[j].z); }
    float s = 0.f;
    #pragma unroll
    for (int j = 0; j < 8; j++) {
        s += p[j].y * __expf(p[j].x - m);
        s += p[j].w * __expf(p[j].z - m);
    }
    rowm[r] = m;
    rowinv[r] = 1.0f / s;
}

// ---------------------------------------------------------------------------
// V pre-transpose (unchanged, validated round 5)
// ---------------------------------------------------------------------------
__global__ __launch_bounds__(256) void vtrans_kernel(
    const float* __restrict__ va, const float* __restrict__ vb,
    short* __restrict__ vT)
{
    int sblk = blockIdx.x;                    // 64
    int bh = blockIdx.y;                      // 16
    int b = bh >> 2, h = bh & 3;
    int hao = (h & 1) * 64, hbo = (h >> 1) * 64;
    __shared__ float vt[32][132];
    int t = threadIdx.x;
    for (int f = t; f < 1024; f += 256) {
        int s = f >> 5, c4 = (f & 31) * 4;
        size_t tok = (size_t)(b * SL + sblk * 32 + s) * 128;
        float4 vv = (c4 < 64) ? *(const float4*)(va + tok + hao + c4)
                              : *(const float4*)(vb + tok + hbo + (c4 - 64));
        *(float4*)&vt[s][c4] = vv;
    }
    __syncthreads();
    int d = t >> 1, shalf = t & 1;
    bf16x8 hi[2], lo[2];
    #pragma unroll
    for (int kb2 = 0; kb2 < 2; kb2++) {
        int kb = shalf * 2 + kb2;
        #pragma unroll
        for (int j = 0; j < 8; j++) {
            float x = vt[kb * 8 + j][d];
            short hh = to_bf16_rne(x);
            float hf = __uint_as_float(((unsigned)(unsigned short)hh) << 16);
            hi[kb2][j] = hh;
            lo[kb2][j] = to_bf16_rne(x - hf);
        }
    }
    size_t base = (((size_t)bh * 64 + sblk) * 128 + d) * 64;
    int d7 = d & 7;
    *(bf16x8*)&vT[base + (size_t)(((2 * (shalf * 2 + 0) + 0) ^ d7) * 8)] = hi[0];
    *(bf16x8*)&vT[base + (size_t)(((2 * (shalf * 2 + 0) + 1) ^ d7) * 8)] = lo[0];
    *(bf16x8*)&vT[base + (size_t)(((2 * (shalf * 2 + 1) + 0) ^ d7) * 8)] = hi[1];
    *(bf16x8*)&vT[base + (size_t)(((2 * (shalf * 2 + 1) + 1) ^ d7) * 8)] = lo[1];
}

// ---------------------------------------------------------------------------
// Fused softmax+PV (validated round-6/7 256-block form)
// ---------------------------------------------------------------------------
__global__ __launch_bounds__(256) void pv_fused_kernel(
    float* __restrict__ attn, const short* __restrict__ vT,
    const float* __restrict__ rowm, const float* __restrict__ rowinv,
    float* __restrict__ outh)
{
    __shared__ short lA[128 * 64];
    __shared__ short lB[128 * 64];

    int bid = blockIdx.x;                     // 256
    int wg = (bid & 7) * 32 + (bid >> 3);     // XCD swizzle
    int bh = wg >> 4, qt = wg & 15;
    int q0 = qt * 128;

    float* Ag = attn + ((size_t)bh * QL + q0) * SL;
    const short* Bg = vT + (size_t)bh * 64 * 8192;

    int t = threadIdx.x;
    int srow = t >> 1, shalf = t & 1;
    int l = t & 63, w = t >> 6;
    int wr = w >> 1, wc = w & 1;
    int lr = l & 15, kb = l >> 4;

    float rm  = rowm[(size_t)bh * QL + q0 + srow];
    float riv = rowinv[(size_t)bh * QL + q0 + srow];

    f32x4 acc[4][4] = {};

    for (int sblk = 0; sblk < 64; sblk++) {
        {
            float* src = Ag + (size_t)srow * SL + sblk * 32 + shalf * 16;
            float x[16];
            #pragma unroll
            for (int j = 0; j < 4; j++)
                *(float4*)&x[j * 4] = *(const float4*)(src + j * 4);
            #pragma unroll
            for (int j = 0; j < 16; j++)
                x[j] = __expf(x[j] - rm) * riv;
            #pragma unroll
            for (int j = 0; j < 4; j++)
                *(float4*)(src + j * 4) = *(float4*)&x[j * 4];
            bf16x8 h0, l0, h1, l1;
            split8(&x[0], h0, l0);
            split8(&x[8], h1, l1);
            int base = srow * 64, r7 = srow & 7;
            *(bf16x8*)&lA[base + (((4 * shalf + 0) ^ r7) * 8)] = h0;
            *(bf16x8*)&lA[base + (((4 * shalf + 1) ^ r7) * 8)] = l0;
            *(bf16x8*)&lA[base + (((4 * shalf + 2) ^ r7) * 8)] = h1;
            *(bf16x8*)&lA[base + (((4 * shalf + 3) ^ r7) * 8)] = l1;
        }
        {
            const bf16x8* src = (const bf16x8*)(Bg + (size_t)sblk * 8192) + t * 4;
            bf16x8 v0 = src[0], v1 = src[1], v2 = src[2], v3 = src[3];
            bf16x8* dst = (bf16x8*)lB + t * 4;
            dst[0] = v0; dst[1] = v1; dst[2] = v2; dst[3] = v3;
        }
        __syncthreads();

        bf16x8 ah[4], al[4], bhv[4], blv[4];
        #pragma unroll
        for (int m = 0; m < 4; m++) {
            int r = wr * 64 + m * 16 + lr;
            int r7 = r & 7, base = r * 64;
            ah[m] = *(bf16x8*)&lA[base + (((2 * kb + 0) ^ r7) * 8)];
            al[m] = *(bf16x8*)&lA[base + (((2 * kb + 1) ^ r7) * 8)];
        }
        #pragma unroll
        for (int n = 0; n < 4; n++) {
            int r = wc * 64 + n * 16 + lr;
            int r7 = r & 7, base = r * 64;
            bhv[n] = *(bf16x8*)&lB[base + (((2 * kb + 0) ^ r7) * 8)];
            blv[n] = *(bf16x8*)&lB[base + (((2 * kb + 1) ^ r7) * 8)];
        }
        #pragma unroll
        for (int m = 0; m < 4; m++) {
            #pragma unroll
            for (int n = 0; n < 4; n++) {
                acc[m][n] = __builtin_amdgcn_mfma_f32_16x16x32_bf16(ah[m], bhv[n], acc[m][n], 0, 0, 0);
                acc[m][n] = __builtin_amdgcn_mfma_f32_16x16x32_bf16(ah[m], blv[n], acc[m][n], 0, 0, 0);
                acc[m][n] = __builtin_amdgcn_mfma_f32_16x16x32_bf16(al[m], bhv[n], acc[m][n], 0, 0, 0);
            }
        }
        __syncthreads();
    }

    #pragma unroll
    for (int n = 0; n < 4; n++) {
        int gd = wc * 64 + n * 16 + lr;
        #pragma unroll
        for (int m = 0; m < 4; m++) {
            int gq = q0 + wr * 64 + m * 16 + kb * 4;
            float* dst = outh + ((size_t)bh * QL + gq) * 128 + gd;
            f32x4 c = acc[m][n];
            dst[0 * 128] = c[0];
            dst[1 * 128] = c[1];
            dst[2 * 128] = c[2];
            dst[3 * 128] = c[3];
        }
    }
}

// ---------------------------------------------------------------------------
// Output projection via split-bf16 MFMA (validated round 10)
// ---------------------------------------------------------------------------
__global__ __launch_bounds__(256) void oproj_mfma_kernel(
    const float* __restrict__ outh, const float* __restrict__ Woa, const float* __restrict__ Wob,
    float* __restrict__ outp)
{
    int bt = blockIdx.x;                  // 64 = 4 b * 16 t-tiles
    int b = bt >> 4, tt = bt & 15;
    int t0 = tt * 128;
    int n0 = blockIdx.y * 128;
    int sel = blockIdx.z;
    const float* W = sel ? Wob : Woa;
    int doff = sel ? 64 : 0;

    __shared__ short lA[128 * 64];
    __shared__ short lB[128 * 64];

    int t = threadIdx.x;
    int srow = t >> 1, shalf = t & 1;
    int l = t & 63, w = t >> 6;
    int wr = w >> 1, wc = w & 1;
    int lr = l & 15, kb = l >> 4;

    f32x4 acc[4][4] = {};

    for (int kc = 0; kc < 256; kc += 32) {
        {
            int k0 = kc + shalf * 16;
            int h = k0 >> 6, d0 = k0 & 63;
            const float* srcA = outh + ((size_t)(b * NH + h) * QL + t0 + srow) * 128 + doff + d0;
            float xa[16];
            #pragma unroll
            for (int j = 0; j < 4; j++)
                *(float4*)&xa[j * 4] = *(const float4*)(srcA + j * 4);
            bf16x8 h0, l0, h1, l1;
            split8(&xa[0], h0, l0);
            split8(&xa[8], h1, l1);
            int base = srow * 64, r7 = srow & 7;
            *(bf16x8*)&lA[base + (((4 * shalf + 0) ^ r7) * 8)] = h0;
            *(bf16x8*)&lA[base + (((4 * shalf + 1) ^ r7) * 8)] = l0;
            *(bf16x8*)&lA[base + (((4 * shalf + 2) ^ r7) * 8)] = h1;
            *(bf16x8*)&lA[base + (((4 * shalf + 3) ^ r7) * 8)] = l1;
        }
        {
            int ncol = srow;
            float xb[16];
            #pragma unroll
            for (int j = 0; j < 16; j++)
                xb[j] = W[(size_t)(kc + shalf * 16 + j) * 256 + n0 + ncol];
            bf16x8 h0, l0, h1, l1;
            split8(&xb[0], h0, l0);
            split8(&xb[8], h1, l1);
            int base = ncol * 64, r7 = ncol & 7;
            *(bf16x8*)&lB[base + (((4 * shalf + 0) ^ r7) * 8)] = h0;
            *(bf16x8*)&lB[base + (((4 * shalf + 1) ^ r7) * 8)] = l0;
            *(bf16x8*)&lB[base + (((4 * shalf + 2) ^ r7) * 8)] = h1;
            *(bf16x8*)&lB[base + (((4 * shalf + 3) ^ r7) * 8)] = l1;
        }
        __syncthreads();

        bf16x8 ah[4], al[4], bhv[4], blv[4];
        #pragma unroll
        for (int m = 0; m < 4; m++) {
            int r = wr * 64 + m * 16 + lr;
            int r7 = r & 7, base = r * 64;
            ah[m] = *(bf16x8*)&lA[base + (((2 * kb + 0) ^ r7) * 8)];
            al[m] = *(bf16x8*)&lA[base + (((2 * kb + 1) ^ r7) * 8)];
        }
        #pragma unroll
        for (int n = 0; n < 4; n++) {
            int r = wc * 64 + n * 16 + lr;
            int r7 = r & 7, base = r * 64;
            bhv[n] = *(bf16x8*)&lB[base + (((2 * kb + 0) ^ r7) * 8)];
            blv[n] = *(bf16x8*)&lB[base + (((2 * kb + 1) ^ r7) * 8)];
        }
        #pragma unroll
        for (int m = 0; m < 4; m++) {
            #pragma unroll
            for (int n = 0; n < 4; n++) {
                acc[m][n] = __builtin_amdgcn_mfma_f32_16x16x32_bf16(ah[m], bhv[n], acc[m][n], 0, 0, 0);
                acc[m][n] = __builtin_amdgcn_mfma_f32_16x16x32_bf16(ah[m], blv[n], acc[m][n], 0, 0, 0);
                acc[m][n] = __builtin_amdgcn_mfma_f32_16x16x32_bf16(al[m], bhv[n], acc[m][n], 0, 0, 0);
            }
        }
        __syncthreads();
    }

    #pragma unroll
    for (int n = 0; n < 4; n++) {
        int gcol = n0 + wc * 64 + n * 16 + lr;
        #pragma unroll
        for (int m = 0; m < 4; m++) {
            int grow = t0 + wr * 64 + m * 16 + kb * 4;
            float* dst = outp + ((size_t)((sel * BS + b) * QL) + grow) * 256 + gcol;
            f32x4 c = acc[m][n];
            dst[0 * 256] = c[0];
            dst[1 * 256] = c[1];
            dst[2 * 256] = c[2];
            dst[3 * 256] = c[3];
        }
    }
}

extern "C" void kernel_launch(void* const* d_in, const int* in_sizes, int n_in,
                              void* d_out, int out_size, void* d_ws, size_t ws_size,
                              hipStream_t stream)
{
    const float* q    = (const float*)d_in[0];
    const float* k    = (const float*)d_in[1];
    const float* v    = (const float*)d_in[2];
    const float* qse  = (const float*)d_in[3];
    const float* kvse = (const float*)d_in[4];
    const float* bias = (const float*)d_in[5];
    const int*   mask = (const int*)d_in[6];
    const float* Wqa  = (const float*)d_in[7];
    const float* Wqb  = (const float*)d_in[8];
    const float* Wka  = (const float*)d_in[9];
    const float* Wkb  = (const float*)d_in[10];
    const float* Wva  = (const float*)d_in[11];
    const float* Wvb  = (const float*)d_in[12];
    const float* Woa  = (const float*)d_in[13];
    const float* Wob  = (const float*)d_in[14];

    float* outp = (float*)d_out;
    float* attn = outp + (size_t)2 * BS * QL * 256;   // attn region of d_out

    float* ws     = (float*)d_ws;
    float* qa     = ws + 0 * FSZ;
    float* qb     = ws + 1 * FSZ;
    float* ka     = ws + 2 * FSZ;
    float* kb     = ws + 3 * FSZ;
    float* va     = ws + 4 * FSZ;
    float* vb     = ws + 5 * FSZ;
    short* qrotS  = (short*)(ws + 6 * FSZ);    // 16.8 MB
    short* krotS  = (short*)(ws + 10 * FSZ);   // 16.8 MB
    float* stats  = ws + 14 * FSZ;             // 4 MB
    float* rowm   = ws + 15 * FSZ;             // 32768 floats
    float* rowinv = ws + 15 * FSZ + 32768;     // 32768 floats
    short* vT     = (short*)(ws + 16 * FSZ);   // 16.8 MB
    float* outh   = ws + 20 * FSZ;             // 16 MB

    proj_mfma_kernel<<<dim3(64, 6), 256, 0, stream>>>(q, k, v, Wqa, Wqb, Wka, Wkb, Wva, Wvb, ws);
    vtrans_kernel<<<dim3(64, 16), 256, 0, stream>>>(va, vb, vT);
    rot_split_kernel<<<dim3(QL, BS, 2), 256, 0, stream>>>(qa, qb, ka, kb, qse, kvse, qrotS, krotS);
    score_mfma_kernel<<<4096, 256, 0, stream>>>(qrotS, krotS, bias, mask, attn, stats);
    sreduce_kernel<<<128, 256, 0, stream>>>(stats, rowm, rowinv);
    pv_fused_kernel<<<256, 256, 0, stream>>>(attn, vT, rowm, rowinv, outh);
    oproj_mfma_kernel<<<dim3(64, 2, 2), 256, 0, stream>>>(outh, Woa, Wob, outp);
}

// Round 13
// 629.014 us; speedup vs baseline: 1.0203x; 1.0203x over previous
//
#include <hip/hip_runtime.h>
#include <math.h>

#define QL 2048
#define SL 2048
#define BS 4
#define NH 4
#define FSZ ((size_t)BS * QL * 128)   // 1,048,576 floats = 4 MB

typedef short bf16x8 __attribute__((ext_vector_type(8)));
typedef float f32x4 __attribute__((ext_vector_type(4)));

__device__ __forceinline__ short to_bf16_rne(float x) {
    unsigned u = __float_as_uint(x);
    unsigned r = u + 0x7fffu + ((u >> 16) & 1u);
    return (short)(r >> 16);
}

__device__ __forceinline__ void split8(const float* x, bf16x8& hi, bf16x8& lo) {
    #pragma unroll
    for (int j = 0; j < 8; j++) {
        short hh = to_bf16_rne(x[j]);
        float hf = __uint_as_float(((unsigned)(unsigned short)hh) << 16);
        hi[j] = hh;
        lo[j] = to_bf16_rne(x[j] - hf);
    }
}

// ---------------------------------------------------------------------------
// Projection GEMM via split-bf16 MFMA (validated round 10)
// ---------------------------------------------------------------------------
__global__ __launch_bounds__(256) void proj_mfma_kernel(
    const float* __restrict__ q, const float* __restrict__ k, const float* __restrict__ v,
    const float* __restrict__ Wqa, const float* __restrict__ Wqb,
    const float* __restrict__ Wka, const float* __restrict__ Wkb,
    const float* __restrict__ Wva, const float* __restrict__ Wvb,
    float* __restrict__ ws)
{
    int id = blockIdx.y;
    const float* X; const float* W;
    const size_t HALF = (size_t)BS * QL * 256;
    switch (id) {
      case 0: X = q;        W = Wqa; break;
      case 1: X = q + HALF; W = Wqb; break;
      case 2: X = k;        W = Wka; break;
      case 3: X = k + HALF; W = Wkb; break;
      case 4: X = v;        W = Wva; break;
      default:X = v + HALF; W = Wvb; break;
    }
    float* Y = ws + (size_t)id * FSZ;
    int m0 = blockIdx.x * 128;

    __shared__ short lA[128 * 64];
    __shared__ short lB[128 * 64];

    int t = threadIdx.x;
    int srow = t >> 1, shalf = t & 1;
    int l = t & 63, w = t >> 6;
    int wr = w >> 1, wc = w & 1;
    int lr = l & 15, kb = l >> 4;

    f32x4 acc[4][4] = {};

    for (int kc = 0; kc < 256; kc += 32) {
        {
            const float* srcA = X + (size_t)(m0 + srow) * 256 + kc + shalf * 16;
            float xa[16];
            #pragma unroll
            for (int j = 0; j < 4; j++)
                *(float4*)&xa[j * 4] = *(const float4*)(srcA + j * 4);
            bf16x8 h0, l0, h1, l1;
            split8(&xa[0], h0, l0);
            split8(&xa[8], h1, l1);
            int base = srow * 64, r7 = srow & 7;
            *(bf16x8*)&lA[base + (((4 * shalf + 0) ^ r7) * 8)] = h0;
            *(bf16x8*)&lA[base + (((4 * shalf + 1) ^ r7) * 8)] = l0;
            *(bf16x8*)&lA[base + (((4 * shalf + 2) ^ r7) * 8)] = h1;
            *(bf16x8*)&lA[base + (((4 * shalf + 3) ^ r7) * 8)] = l1;
        }
        {
            int ncol = srow;
            float xb[16];
            #pragma unroll
            for (int j = 0; j < 16; j++)
                xb[j] = W[(size_t)(kc + shalf * 16 + j) * 128 + ncol];
            bf16x8 h0, l0, h1, l1;
            split8(&xb[0], h0, l0);
            split8(&xb[8], h1, l1);
            int base = ncol * 64, r7 = ncol & 7;
            *(bf16x8*)&lB[base + (((4 * shalf + 0) ^ r7) * 8)] = h0;
            *(bf16x8*)&lB[base + (((4 * shalf + 1) ^ r7) * 8)] = l0;
            *(bf16x8*)&lB[base + (((4 * shalf + 2) ^ r7) * 8)] = h1;
            *(bf16x8*)&lB[base + (((4 * shalf + 3) ^ r7) * 8)] = l1;
        }
        __syncthreads();

        bf16x8 ah[4], al[4], bhv[4], blv[4];
        #pragma unroll
        for (int m = 0; m < 4; m++) {
            int r = wr * 64 + m * 16 + lr;
            int r7 = r & 7, base = r * 64;
            ah[m] = *(bf16x8*)&lA[base + (((2 * kb + 0) ^ r7) * 8)];
            al[m] = *(bf16x8*)&lA[base + (((2 * kb + 1) ^ r7) * 8)];
        }
        #pragma unroll
        for (int n = 0; n < 4; n++) {
            int r = wc * 64 + n * 16 + lr;
            int r7 = r & 7, base = r * 64;
            bhv[n] = *(bf16x8*)&lB[base + (((2 * kb + 0) ^ r7) * 8)];
            blv[n] = *(bf16x8*)&lB[base + (((2 * kb + 1) ^ r7) * 8)];
        }
        #pragma unroll
        for (int m = 0; m < 4; m++) {
            #pragma unroll
            for (int n = 0; n < 4; n++) {
                acc[m][n] = __builtin_amdgcn_mfma_f32_16x16x32_bf16(ah[m], bhv[n], acc[m][n], 0, 0, 0);
                acc[m][n] = __builtin_amdgcn_mfma_f32_16x16x32_bf16(ah[m], blv[n], acc[m][n], 0, 0, 0);
                acc[m][n] = __builtin_amdgcn_mfma_f32_16x16x32_bf16(al[m], bhv[n], acc[m][n], 0, 0, 0);
            }
        }
        __syncthreads();
    }

    #pragma unroll
    for (int n = 0; n < 4; n++) {
        int gcol = wc * 64 + n * 16 + lr;
        #pragma unroll
        for (int m = 0; m < 4; m++) {
            int grow = m0 + wr * 64 + m * 16 + kb * 4;
            float* dst = Y + (size_t)grow * 128 + gcol;
            f32x4 c = acc[m][n];
            dst[0 * 128] = c[0];
            dst[1 * 128] = c[1];
            dst[2 * 128] = c[2];
            dst[3 * 128] = c[3];
        }
    }
}

// ---------------------------------------------------------------------------
// Spatial rotation -> split-bf16 pre-swizzled planes; z selects q vs kv.
// ---------------------------------------------------------------------------
__global__ __launch_bounds__(256) void rot_split_kernel(
    const float* __restrict__ qa, const float* __restrict__ qb,
    const float* __restrict__ ka, const float* __restrict__ kb,
    const float* __restrict__ qse, const float* __restrict__ kvse,
    short* __restrict__ qrotS, short* __restrict__ krotS)
{
    int tkn = blockIdx.x;
    int b = blockIdx.y;
    int z = blockIdx.z;                       // 0 = q, 1 = kv
    const float* ha = z ? ka : qa;
    const float* hb = z ? kb : qb;
    const float* E = z ? (kvse + (size_t)(b * SL + tkn) * 16384)
                       : (qse + (size_t)b * 16384);
    short* rotS = z ? krotS : qrotS;

    __shared__ float hv[4][128];
    __shared__ float outl[4][128];
    int tid = threadIdx.x;
    size_t tok = (size_t)(b * QL + tkn) * 128;
    for (int idx = tid; idx < 512; idx += 256) {
        int h = idx >> 7, d = idx & 127;
        float val = (d < 64) ? ha[tok + (h & 1) * 64 + d]
                             : hb[tok + (h >> 1) * 64 + (d - 64)];
        hv[h][d] = val;
    }
    __syncthreads();
    int w = tid >> 6, lane = tid & 63;
    int half = lane >> 5, l5 = lane & 31;
    for (int it = 0; it < 16; ++it) {
        int i = w * 32 + it * 2 + half;
        float4 e = *(const float4*)(E + (size_t)i * 128 + l5 * 4);
        float acc[4];
        #pragma unroll
        for (int h = 0; h < 4; h++) {
            float4 x = *(const float4*)&hv[h][l5 * 4];
            acc[h] = e.x * x.x + e.y * x.y + e.z * x.z + e.w * x.w;
        }
        #pragma unroll
        for (int off = 1; off < 32; off <<= 1) {
            #pragma unroll
            for (int h = 0; h < 4; h++) acc[h] += __shfl_xor(acc[h], off);
        }
        if (l5 < 4) outl[l5][i] = acc[l5];
    }
    __syncthreads();
    if (tid < 128) {
        int h    = tid >> 5;
        int kcid = (tid >> 3) & 3;
        int s    = tid & 7;
        int shalf = s >> 2;
        int isLo  = s & 1;
        int jbase = ((s >> 1) & 1) * 8;
        int dbase = kcid * 32 + shalf * 16 + jbase;
        bf16x8 outv;
        #pragma unroll
        for (int j = 0; j < 8; j++) {
            float x = outl[h][dbase + j];
            short hh = to_bf16_rne(x);
            if (isLo) {
                float hf = __uint_as_float(((unsigned)(unsigned short)hh) << 16);
                outv[j] = to_bf16_rne(x - hf);
            } else {
                outv[j] = hh;
            }
        }
        int bh = b * NH + h;
        int row = tkn & 127;
        size_t base = ((((size_t)bh * 16 + (tkn >> 7)) * 4 + kcid) * 128 + row) * 64;
        *(bf16x8*)&rotS[base + (size_t)((s ^ (row & 7)) * 8)] = outv;
    }
}

// ---------------------------------------------------------------------------
// Score GEMM via split-bf16 MFMA + fused softmax partials.
// Staging now via global_load_lds (async DMA, no VGPR round-trip);
// S-store reverted to the validated round-10 direct form.
// ---------------------------------------------------------------------------
__global__ __launch_bounds__(256) void score_mfma_kernel(
    const short* __restrict__ qrotS, const short* __restrict__ krotS,
    const float* __restrict__ bias, const int* __restrict__ mask,
    float* __restrict__ attn, float* __restrict__ stats)
{
    __shared__ short lA[128 * 64];
    __shared__ short lB[128 * 64];
    __shared__ float redM[128][2];
    __shared__ float redS[128][2];

    int bid = blockIdx.x;                       // 4096
    int wg = (bid & 7) * 512 + (bid >> 3);      // XCD-chunked swizzle
    int bh = wg >> 8;
    int qt = (wg >> 4) & 15, st = wg & 15;
    int q0 = qt * 128, s0 = st * 128;
    int b = bh >> 2;

    int t = threadIdx.x;
    int l = t & 63, w = t >> 6;
    int wr = w >> 1, wc = w & 1;
    int lr = l & 15, kb = l >> 4;

    const char* Abase = (const char*)(qrotS + (((size_t)bh * 16 + qt) * 4) * 8192);
    const char* Bbase = (const char*)(krotS + (((size_t)bh * 16 + st) * 4) * 8192);
    int lin = w * 4096 + l * 16;                // linear byte offset, lane-stride 16

    f32x4 acc[4][4] = {};

    for (int kcid = 0; kcid < 4; kcid++) {
        {
            const char* srcA = Abase + (size_t)kcid * 16384 + lin;
            const char* srcB = Bbase + (size_t)kcid * 16384 + lin;
            char* dA = (char*)lA + lin;
            char* dB = (char*)lB + lin;
            #pragma unroll
            for (int j = 0; j < 4; j++) {
                __builtin_amdgcn_global_load_lds((const unsigned int*)(srcA + j * 1024),
                                                 (unsigned int*)(dA + j * 1024), 16, 0, 0);
                __builtin_amdgcn_global_load_lds((const unsigned int*)(srcB + j * 1024),
                                                 (unsigned int*)(dB + j * 1024), 16, 0, 0);
            }
        }
        __syncthreads();

        bf16x8 ah[4], al[4], bhv[4], blv[4];
        #pragma unroll
        for (int m = 0; m < 4; m++) {
            int r = wr * 64 + m * 16 + lr;
            int r7 = r & 7, base = r * 64;
            ah[m] = *(bf16x8*)&lA[base + (((2 * kb + 0) ^ r7) * 8)];
            al[m] = *(bf16x8*)&lA[base + (((2 * kb + 1) ^ r7) * 8)];
        }
        #pragma unroll
        for (int n = 0; n < 4; n++) {
            int r = wc * 64 + n * 16 + lr;
            int r7 = r & 7, base = r * 64;
            bhv[n] = *(bf16x8*)&lB[base + (((2 * kb + 0) ^ r7) * 8)];
            blv[n] = *(bf16x8*)&lB[base + (((2 * kb + 1) ^ r7) * 8)];
        }
        #pragma unroll
        for (int m = 0; m < 4; m++) {
            #pragma unroll
            for (int n = 0; n < 4; n++) {
                acc[m][n] = __builtin_amdgcn_mfma_f32_16x16x32_bf16(ah[m], bhv[n], acc[m][n], 0, 0, 0);
                acc[m][n] = __builtin_amdgcn_mfma_f32_16x16x32_bf16(ah[m], blv[n], acc[m][n], 0, 0, 0);
                acc[m][n] = __builtin_amdgcn_mfma_f32_16x16x32_bf16(al[m], bhv[n], acc[m][n], 0, 0, 0);
            }
        }
        __syncthreads();
    }

    // ---- epilogue: finalize S in registers, write raw S (round-10 form) ----
    const float scale = 0.08838834764831845f;   // 1/sqrt(128)
    #pragma unroll
    for (int n = 0; n < 4; n++) {
        int gs = s0 + wc * 64 + n * 16 + lr;
        float adj = -1e9f * (float)mask[b * SL + gs] - bias[b * SL + gs];
        #pragma unroll
        for (int m = 0; m < 4; m++) {
            int gq = q0 + wr * 64 + m * 16 + kb * 4;
            float* dst = attn + ((size_t)bh * QL + gq) * SL + gs;
            f32x4 c = acc[m][n];
            c[0] = c[0] * scale + adj;
            c[1] = c[1] * scale + adj;
            c[2] = c[2] * scale + adj;
            c[3] = c[3] * scale + adj;
            acc[m][n] = c;
            dst[0 * SL] = c[0];
            dst[1 * SL] = c[1];
            dst[2 * SL] = c[2];
            dst[3 * SL] = c[3];
        }
    }

    // ---- per-row tile max ----
    #pragma unroll
    for (int m = 0; m < 4; m++) {
        #pragma unroll
        for (int i = 0; i < 4; i++) {
            float rm = fmaxf(fmaxf(acc[m][0][i], acc[m][1][i]),
                             fmaxf(acc[m][2][i], acc[m][3][i]));
            rm = fmaxf(rm, __shfl_xor(rm, 1));
            rm = fmaxf(rm, __shfl_xor(rm, 2));
            rm = fmaxf(rm, __shfl_xor(rm, 4));
            rm = fmaxf(rm, __shfl_xor(rm, 8));
            if (lr == 0) redM[wr * 64 + m * 16 + kb * 4 + i][wc] = rm;
        }
    }
    __syncthreads();
    // ---- per-row tile expsum relative to combined tile max ----
    #pragma unroll
    for (int m = 0; m < 4; m++) {
        #pragma unroll
        for (int i = 0; i < 4; i++) {
            int row = wr * 64 + m * 16 + kb * 4 + i;
            float mt = fmaxf(redM[row][0], redM[row][1]);
            float es = __expf(acc[m][0][i] - mt) + __expf(acc[m][1][i] - mt)
                     + __expf(acc[m][2][i] - mt) + __expf(acc[m][3][i] - mt);
            es += __shfl_xor(es, 1);
            es += __shfl_xor(es, 2);
            es += __shfl_xor(es, 4);
            es += __shfl_xor(es, 8);
            if (lr == 0) redS[row][wc] = es;
        }
    }
    __syncthreads();
    if (t < 128) {
        float mt = fmaxf(redM[t][0], redM[t][1]);
        float es = redS[t][0] + redS[t][1];
        size_t r = (size_t)bh * QL + q0 + t;
        stats[(r * 16 + st) * 2 + 0] = mt;
        stats[(r * 16 + st) * 2 + 1] = es;
    }
}

// ---------------------------------------------------------------------------
// Flash combine: per row, 16 (max, expsum) partials -> rowmax, 1/rowsum.
// ---------------------------------------------------------------------------
__global__ __launch_bounds__(256) void sreduce_kernel(
    const float* __restrict__ stats,
    float* __restrict__ rowm, float* __restrict__ rowinv)
{
    int r = blockIdx.x * 256 + threadIdx.x;     // 32768 rows
    const float* src = stats + (size_t)r * 32;
    float4 p[8];
    #pragma unroll
    for (int j = 0; j < 8; j++) p[j] = *(const float4*)(src + j * 4);
    float m = -INFINITY;
    #pragma unroll
    for (int j = 0; j < 8; j++) { m = fmaxf(m, p[j].x); m = fmaxf(m, p[j].z); }
    float s = 0.f;
    #pragma unroll
    for (int j = 0; j < 8; j++) {
        s += p[j].y * __expf(p[j].x - m);
        s += p[j].w * __expf(p[j].z - m);
    }
    rowm[r] = m;
    rowinv[r] = 1.0f / s;
}

// ---------------------------------------------------------------------------
// V pre-transpose (unchanged, validated round 5)
// ---------------------------------------------------------------------------
__global__ __launch_bounds__(256) void vtrans_kernel(
    const float* __restrict__ va, const float* __restrict__ vb,
    short* __restrict__ vT)
{
    int sblk = blockIdx.x;                    // 64
    int bh = blockIdx.y;                      // 16
    int b = bh >> 2, h = bh & 3;
    int hao = (h & 1) * 64, hbo = (h >> 1) * 64;
    __shared__ float vt[32][132];
    int t = threadIdx.x;
    for (int f = t; f < 1024; f += 256) {
        int s = f >> 5, c4 = (f & 31) * 4;
        size_t tok = (size_t)(b * SL + sblk * 32 + s) * 128;
        float4 vv = (c4 < 64) ? *(const float4*)(va + tok + hao + c4)
                              : *(const float4*)(vb + tok + hbo + (c4 - 64));
        *(float4*)&vt[s][c4] = vv;
    }
    __syncthreads();
    int d = t >> 1, shalf = t & 1;
    bf16x8 hi[2], lo[2];
    #pragma unroll
    for (int kb2 = 0; kb2 < 2; kb2++) {
        int kb = shalf * 2 + kb2;
        #pragma unroll
        for (int j = 0; j < 8; j++) {
            float x = vt[kb * 8 + j][d];
            short hh = to_bf16_rne(x);
            float hf = __uint_as_float(((unsigned)(unsigned short)hh) << 16);
            hi[kb2][j] = hh;
            lo[kb2][j] = to_bf16_rne(x - hf);
        }
    }
    size_t base = (((size_t)bh * 64 + sblk) * 128 + d) * 64;
    int d7 = d & 7;
    *(bf16x8*)&vT[base + (size_t)(((2 * (shalf * 2 + 0) + 0) ^ d7) * 8)] = hi[0];
    *(bf16x8*)&vT[base + (size_t)(((2 * (shalf * 2 + 0) + 1) ^ d7) * 8)] = lo[0];
    *(bf16x8*)&vT[base + (size_t)(((2 * (shalf * 2 + 1) + 0) ^ d7) * 8)] = hi[1];
    *(bf16x8*)&vT[base + (size_t)(((2 * (shalf * 2 + 1) + 1) ^ d7) * 8)] = lo[1];
}

// ---------------------------------------------------------------------------
// Fused softmax+PV; B-staging via global_load_lds, A-staging reg-based (exp).
// ---------------------------------------------------------------------------
__global__ __launch_bounds__(256) void pv_fused_kernel(
    float* __restrict__ attn, const short* __restrict__ vT,
    const float* __restrict__ rowm, const float* __restrict__ rowinv,
    float* __restrict__ outh)
{
    __shared__ short lA[128 * 64];
    __shared__ short lB[128 * 64];

    int bid = blockIdx.x;                     // 256
    int wg = (bid & 7) * 32 + (bid >> 3);     // XCD swizzle
    int bh = wg >> 4, qt = wg & 15;
    int q0 = qt * 128;

    float* Ag = attn + ((size_t)bh * QL + q0) * SL;
    const char* Bg = (const char*)(vT + (size_t)bh * 64 * 8192);

    int t = threadIdx.x;
    int srow = t >> 1, shalf = t & 1;
    int l = t & 63, w = t >> 6;
    int wr = w >> 1, wc = w & 1;
    int lr = l & 15, kb = l >> 4;
    int lin = w * 4096 + l * 16;

    float rm  = rowm[(size_t)bh * QL + q0 + srow];
    float riv = rowinv[(size_t)bh * QL + q0 + srow];

    f32x4 acc[4][4] = {};

    for (int sblk = 0; sblk < 64; sblk++) {
        // stage B first (async DMA, overlaps with A's VALU work)
        {
            const char* srcB = Bg + (size_t)sblk * 16384 + lin;
            char* dB = (char*)lB + lin;
            #pragma unroll
            for (int j = 0; j < 4; j++) {
                __builtin_amdgcn_global_load_lds((const unsigned int*)(srcB + j * 1024),
                                                 (unsigned int*)(dB + j * 1024), 16, 0, 0);
            }
        }
        // stage A: raw S -> P = exp(S-m)*inv; write P back; split hi/lo
        {
            float* src = Ag + (size_t)srow * SL + sblk * 32 + shalf * 16;
            float x[16];
            #pragma unroll
            for (int j = 0; j < 4; j++)
                *(float4*)&x[j * 4] = *(const float4*)(src + j * 4);
            #pragma unroll
            for (int j = 0; j < 16; j++)
                x[j] = __expf(x[j] - rm) * riv;
            #pragma unroll
            for (int j = 0; j < 4; j++)
                *(float4*)(src + j * 4) = *(float4*)&x[j * 4];
            bf16x8 h0, l0, h1, l1;
            split8(&x[0], h0, l0);
            split8(&x[8], h1, l1);
            int base = srow * 64, r7 = srow & 7;
            *(bf16x8*)&lA[base + (((4 * shalf + 0) ^ r7) * 8)] = h0;
            *(bf16x8*)&lA[base + (((4 * shalf + 1) ^ r7) * 8)] = l0;
            *(bf16x8*)&lA[base + (((4 * shalf + 2) ^ r7) * 8)] = h1;
            *(bf16x8*)&lA[base + (((4 * shalf + 3) ^ r7) * 8)] = l1;
        }
        __syncthreads();

        bf16x8 ah[4], al[4], bhv[4], blv[4];
        #pragma unroll
        for (int m = 0; m < 4; m++) {
            int r = wr * 64 + m * 16 + lr;
            int r7 = r & 7, base = r * 64;
            ah[m] = *(bf16x8*)&lA[base + (((2 * kb + 0) ^ r7) * 8)];
            al[m] = *(bf16x8*)&lA[base + (((2 * kb + 1) ^ r7) * 8)];
        }
        #pragma unroll
        for (int n = 0; n < 4; n++) {
            int r = wc * 64 + n * 16 + lr;
            int r7 = r & 7, base = r * 64;
            bhv[n] = *(bf16x8*)&lB[base + (((2 * kb + 0) ^ r7) * 8)];
            blv[n] = *(bf16x8*)&lB[base + (((2 * kb + 1) ^ r7) * 8)];
        }
        #pragma unroll
        for (int m = 0; m < 4; m++) {
            #pragma unroll
            for (int n = 0; n < 4; n++) {
                acc[m][n] = __builtin_amdgcn_mfma_f32_16x16x32_bf16(ah[m], bhv[n], acc[m][n], 0, 0, 0);
                acc[m][n] = __builtin_amdgcn_mfma_f32_16x16x32_bf16(ah[m], blv[n], acc[m][n], 0, 0, 0);
                acc[m][n] = __builtin_amdgcn_mfma_f32_16x16x32_bf16(al[m], bhv[n], acc[m][n], 0, 0, 0);
            }
        }
        __syncthreads();
    }

    #pragma unroll
    for (int n = 0; n < 4; n++) {
        int gd = wc * 64 + n * 16 + lr;
        #pragma unroll
        for (int m = 0; m < 4; m++) {
            int gq = q0 + wr * 64 + m * 16 + kb * 4;
            float* dst = outh + ((size_t)bh * QL + gq) * 128 + gd;
            f32x4 c = acc[m][n];
            dst[0 * 128] = c[0];
            dst[1 * 128] = c[1];
            dst[2 * 128] = c[2];
            dst[3 * 128] = c[3];
        }
    }
}

// ---------------------------------------------------------------------------
// Output projection via split-bf16 MFMA (validated round 10)
// ---------------------------------------------------------------------------
__global__ __launch_bounds__(256) void oproj_mfma_kernel(
    const float* __restrict__ outh, const float* __restrict__ Woa, const float* __restrict__ Wob,
    float* __restrict__ outp)
{
    int bt = blockIdx.x;                  // 64 = 4 b * 16 t-tiles
    int b = bt >> 4, tt = bt & 15;
    int t0 = tt * 128;
    int n0 = blockIdx.y * 128;
    int sel = blockIdx.z;
    const float* W = sel ? Wob : Woa;
    int doff = sel ? 64 : 0;

    __shared__ short lA[128 * 64];
    __shared__ short lB[128 * 64];

    int t = threadIdx.x;
    int srow = t >> 1, shalf = t & 1;
    int l = t & 63, w = t >> 6;
    int wr = w >> 1, wc = w & 1;
    int lr = l & 15, kb = l >> 4;

    f32x4 acc[4][4] = {};

    for (int kc = 0; kc < 256; kc += 32) {
        {
            int k0 = kc + shalf * 16;
            int h = k0 >> 6, d0 = k0 & 63;
            const float* srcA = outh + ((size_t)(b * NH + h) * QL + t0 + srow) * 128 + doff + d0;
            float xa[16];
            #pragma unroll
            for (int j = 0; j < 4; j++)
                *(float4*)&xa[j * 4] = *(const float4*)(srcA + j * 4);
            bf16x8 h0, l0, h1, l1;
            split8(&xa[0], h0, l0);
            split8(&xa[8], h1, l1);
            int base = srow * 64, r7 = srow & 7;
            *(bf16x8*)&lA[base + (((4 * shalf + 0) ^ r7) * 8)] = h0;
            *(bf16x8*)&lA[base + (((4 * shalf + 1) ^ r7) * 8)] = l0;
            *(bf16x8*)&lA[base + (((4 * shalf + 2) ^ r7) * 8)] = h1;
            *(bf16x8*)&lA[base + (((4 * shalf + 3) ^ r7) * 8)] = l1;
        }
        {
            int ncol = srow;
            float xb[16];
            #pragma unroll
            for (int j = 0; j < 16; j++)
                xb[j] = W[(size_t)(kc + shalf * 16 + j) * 256 + n0 + ncol];
            bf16x8 h0, l0, h1, l1;
            split8(&xb[0], h0, l0);
            split8(&xb[8], h1, l1);
            int base = ncol * 64, r7 = ncol & 7;
            *(bf16x8*)&lB[base + (((4 * shalf + 0) ^ r7) * 8)] = h0;
            *(bf16x8*)&lB[base + (((4 * shalf + 1) ^ r7) * 8)] = l0;
            *(bf16x8*)&lB[base + (((4 * shalf + 2) ^ r7) * 8)] = h1;
            *(bf16x8*)&lB[base + (((4 * shalf + 3) ^ r7) * 8)] = l1;
        }
        __syncthreads();

        bf16x8 ah[4], al[4], bhv[4], blv[4];
        #pragma unroll
        for (int m = 0; m < 4; m++) {
            int r = wr * 64 + m * 16 + lr;
            int r7 = r & 7, base = r * 64;
            ah[m] = *(bf16x8*)&lA[base + (((2 * kb + 0) ^ r7) * 8)];
            al[m] = *(bf16x8*)&lA[base + (((2 * kb + 1) ^ r7) * 8)];
        }
        #pragma unroll
        for (int n = 0; n < 4; n++) {
            int r = wc * 64 + n * 16 + lr;
            int r7 = r & 7, base = r * 64;
            bhv[n] = *(bf16x8*)&lB[base + (((2 * kb + 0) ^ r7) * 8)];
            blv[n] = *(bf16x8*)&lB[base + (((2 * kb + 1) ^ r7) * 8)];
        }
        #pragma unroll
        for (int m = 0; m < 4; m++) {
            #pragma unroll
            for (int n = 0; n < 4; n++) {
                acc[m][n] = __builtin_amdgcn_mfma_f32_16x16x32_bf16(ah[m], bhv[n], acc[m][n], 0, 0, 0);
                acc[m][n] = __builtin_amdgcn_mfma_f32_16x16x32_bf16(ah[m], blv[n], acc[m][n], 0, 0, 0);
                acc[m][n] = __builtin_amdgcn_mfma_f32_16x16x32_bf16(al[m], bhv[n], acc[m][n], 0, 0, 0);
            }
        }
        __syncthreads();
    }

    #pragma unroll
    for (int n = 0; n < 4; n++) {
        int gcol = n0 + wc * 64 + n * 16 + lr;
        #pragma unroll
        for (int m = 0; m < 4; m++) {
            int grow = t0 + wr * 64 + m * 16 + kb * 4;
            float* dst = outp + ((size_t)((sel * BS + b) * QL) + grow) * 256 + gcol;
            f32x4 c = acc[m][n];
            dst[0 * 256] = c[0];
            dst[1 * 256] = c[1];
            dst[2 * 256] = c[2];
            dst[3 * 256] = c[3];
        }
    }
}

extern "C" void kernel_launch(void* const* d_in, const int* in_sizes, int n_in,
                              void* d_out, int out_size, void* d_ws, size_t ws_size,
                              hipStream_t stream)
{
    const float* q    = (const float*)d_in[0];
    const float* k    = (const float*)d_in[1];
    const float* v    = (const float*)d_in[2];
    const float* qse  = (const float*)d_in[3];
    const float* kvse = (const float*)d_in[4];
    const float* bias = (const float*)d_in[5];
    const int*   mask = (const int*)d_in[6];
    const float* Wqa  = (const float*)d_in[7];
    const float* Wqb  = (const float*)d_in[8];
    const float* Wka  = (const float*)d_in[9];
    const float* Wkb  = (const float*)d_in[10];
    const float* Wva  = (const float*)d_in[11];
    const float* Wvb  = (const float*)d_in[12];
    const float* Woa  = (const float*)d_in[13];
    const float* Wob  = (const float*)d_in[14];

    float* outp = (float*)d_out;
    float* attn = outp + (size_t)2 * BS * QL * 256;   // attn region of d_out

    float* ws     = (float*)d_ws;
    float* qa     = ws + 0 * FSZ;
    float* qb     = ws + 1 * FSZ;
    float* ka     = ws + 2 * FSZ;
    float* kb     = ws + 3 * FSZ;
    float* va     = ws + 4 * FSZ;
    float* vb     = ws + 5 * FSZ;
    short* qrotS  = (short*)(ws + 6 * FSZ);    // 16.8 MB
    short* krotS  = (short*)(ws + 10 * FSZ);   // 16.8 MB
    float* stats  = ws + 14 * FSZ;             // 4 MB
    float* rowm   = ws + 15 * FSZ;             // 32768 floats
    float* rowinv = ws + 15 * FSZ + 32768;     // 32768 floats
    short* vT     = (short*)(ws + 16 * FSZ);   // 16.8 MB
    float* outh   = ws + 20 * FSZ;             // 16 MB

    proj_mfma_kernel<<<dim3(64, 6), 256, 0, stream>>>(q, k, v, Wqa, Wqb, Wka, Wkb, Wva, Wvb, ws);
    vtrans_kernel<<<dim3(64, 16), 256, 0, stream>>>(va, vb, vT);
    rot_split_kernel<<<dim3(QL, BS, 2), 256, 0, stream>>>(qa, qb, ka, kb, qse, kvse, qrotS, krotS);
    score_mfma_kernel<<<4096, 256, 0, stream>>>(qrotS, krotS, bias, mask, attn, stats);
    sreduce_kernel<<<128, 256, 0, stream>>>(stats, rowm, rowinv);
    pv_fused_kernel<<<256, 256, 0, stream>>>(attn, vT, rowm, rowinv, outh);
    oproj_mfma_kernel<<<dim3(64, 2, 2), 256, 0, stream>>>(outh, Woa, Wob, outp);
}

// Round 14
// 618.343 us; speedup vs baseline: 1.0379x; 1.0173x over previous
//
#include <hip/hip_runtime.h>
#include <math.h>

#define QL 2048
#define SL 2048
#define BS 4
#define NH 4
#define FSZ ((size_t)BS * QL * 128)   // 1,048,576 floats = 4 MB
#define OSZ ((size_t)2 * BS * QL * 256)  // 4,194,304 floats

typedef short bf16x8 __attribute__((ext_vector_type(8)));
typedef float f32x4 __attribute__((ext_vector_type(4)));

__device__ __forceinline__ short to_bf16_rne(float x) {
    unsigned u = __float_as_uint(x);
    unsigned r = u + 0x7fffu + ((u >> 16) & 1u);
    return (short)(r >> 16);
}

__device__ __forceinline__ void split8(const float* x, bf16x8& hi, bf16x8& lo) {
    #pragma unroll
    for (int j = 0; j < 8; j++) {
        short hh = to_bf16_rne(x[j]);
        float hf = __uint_as_float(((unsigned)(unsigned short)hh) << 16);
        hi[j] = hh;
        lo[j] = to_bf16_rne(x[j] - hf);
    }
}

// ---------------------------------------------------------------------------
// Projection GEMM via split-bf16 MFMA (validated round 10)
// ---------------------------------------------------------------------------
__global__ __launch_bounds__(256) void proj_mfma_kernel(
    const float* __restrict__ q, const float* __restrict__ k, const float* __restrict__ v,
    const float* __restrict__ Wqa, const float* __restrict__ Wqb,
    const float* __restrict__ Wka, const float* __restrict__ Wkb,
    const float* __restrict__ Wva, const float* __restrict__ Wvb,
    float* __restrict__ ws)
{
    int id = blockIdx.y;
    const float* X; const float* W;
    const size_t HALF = (size_t)BS * QL * 256;
    switch (id) {
      case 0: X = q;        W = Wqa; break;
      case 1: X = q + HALF; W = Wqb; break;
      case 2: X = k;        W = Wka; break;
      case 3: X = k + HALF; W = Wkb; break;
      case 4: X = v;        W = Wva; break;
      default:X = v + HALF; W = Wvb; break;
    }
    float* Y = ws + (size_t)id * FSZ;
    int m0 = blockIdx.x * 128;

    __shared__ short lA[128 * 64];
    __shared__ short lB[128 * 64];

    int t = threadIdx.x;
    int srow = t >> 1, shalf = t & 1;
    int l = t & 63, w = t >> 6;
    int wr = w >> 1, wc = w & 1;
    int lr = l & 15, kb = l >> 4;

    f32x4 acc[4][4] = {};

    for (int kc = 0; kc < 256; kc += 32) {
        {
            const float* srcA = X + (size_t)(m0 + srow) * 256 + kc + shalf * 16;
            float xa[16];
            #pragma unroll
            for (int j = 0; j < 4; j++)
                *(float4*)&xa[j * 4] = *(const float4*)(srcA + j * 4);
            bf16x8 h0, l0, h1, l1;
            split8(&xa[0], h0, l0);
            split8(&xa[8], h1, l1);
            int base = srow * 64, r7 = srow & 7;
            *(bf16x8*)&lA[base + (((4 * shalf + 0) ^ r7) * 8)] = h0;
            *(bf16x8*)&lA[base + (((4 * shalf + 1) ^ r7) * 8)] = l0;
            *(bf16x8*)&lA[base + (((4 * shalf + 2) ^ r7) * 8)] = h1;
            *(bf16x8*)&lA[base + (((4 * shalf + 3) ^ r7) * 8)] = l1;
        }
        {
            int ncol = srow;
            float xb[16];
            #pragma unroll
            for (int j = 0; j < 16; j++)
                xb[j] = W[(size_t)(kc + shalf * 16 + j) * 128 + ncol];
            bf16x8 h0, l0, h1, l1;
            split8(&xb[0], h0, l0);
            split8(&xb[8], h1, l1);
            int base = ncol * 64, r7 = ncol & 7;
            *(bf16x8*)&lB[base + (((4 * shalf + 0) ^ r7) * 8)] = h0;
            *(bf16x8*)&lB[base + (((4 * shalf + 1) ^ r7) * 8)] = l0;
            *(bf16x8*)&lB[base + (((4 * shalf + 2) ^ r7) * 8)] = h1;
            *(bf16x8*)&lB[base + (((4 * shalf + 3) ^ r7) * 8)] = l1;
        }
        __syncthreads();

        bf16x8 ah[4], al[4], bhv[4], blv[4];
        #pragma unroll
        for (int m = 0; m < 4; m++) {
            int r = wr * 64 + m * 16 + lr;
            int r7 = r & 7, base = r * 64;
            ah[m] = *(bf16x8*)&lA[base + (((2 * kb + 0) ^ r7) * 8)];
            al[m] = *(bf16x8*)&lA[base + (((2 * kb + 1) ^ r7) * 8)];
        }
        #pragma unroll
        for (int n = 0; n < 4; n++) {
            int r = wc * 64 + n * 16 + lr;
            int r7 = r & 7, base = r * 64;
            bhv[n] = *(bf16x8*)&lB[base + (((2 * kb + 0) ^ r7) * 8)];
            blv[n] = *(bf16x8*)&lB[base + (((2 * kb + 1) ^ r7) * 8)];
        }
        #pragma unroll
        for (int m = 0; m < 4; m++) {
            #pragma unroll
            for (int n = 0; n < 4; n++) {
                acc[m][n] = __builtin_amdgcn_mfma_f32_16x16x32_bf16(ah[m], bhv[n], acc[m][n], 0, 0, 0);
                acc[m][n] = __builtin_amdgcn_mfma_f32_16x16x32_bf16(ah[m], blv[n], acc[m][n], 0, 0, 0);
                acc[m][n] = __builtin_amdgcn_mfma_f32_16x16x32_bf16(al[m], bhv[n], acc[m][n], 0, 0, 0);
            }
        }
        __syncthreads();
    }

    #pragma unroll
    for (int n = 0; n < 4; n++) {
        int gcol = wc * 64 + n * 16 + lr;
        #pragma unroll
        for (int m = 0; m < 4; m++) {
            int grow = m0 + wr * 64 + m * 16 + kb * 4;
            float* dst = Y + (size_t)grow * 128 + gcol;
            f32x4 c = acc[m][n];
            dst[0 * 128] = c[0];
            dst[1 * 128] = c[1];
            dst[2 * 128] = c[2];
            dst[3 * 128] = c[3];
        }
    }
}

// ---------------------------------------------------------------------------
// Spatial rotation -> split-bf16 pre-swizzled planes; z selects q vs kv.
// ---------------------------------------------------------------------------
__global__ __launch_bounds__(256) void rot_split_kernel(
    const float* __restrict__ qa, const float* __restrict__ qb,
    const float* __restrict__ ka, const float* __restrict__ kb,
    const float* __restrict__ qse, const float* __restrict__ kvse,
    short* __restrict__ qrotS, short* __restrict__ krotS)
{
    int tkn = blockIdx.x;
    int b = blockIdx.y;
    int z = blockIdx.z;                       // 0 = q, 1 = kv
    const float* ha = z ? ka : qa;
    const float* hb = z ? kb : qb;
    const float* E = z ? (kvse + (size_t)(b * SL + tkn) * 16384)
                       : (qse + (size_t)b * 16384);
    short* rotS = z ? krotS : qrotS;

    __shared__ float hv[4][128];
    __shared__ float outl[4][128];
    int tid = threadIdx.x;
    size_t tok = (size_t)(b * QL + tkn) * 128;
    for (int idx = tid; idx < 512; idx += 256) {
        int h = idx >> 7, d = idx & 127;
        float val = (d < 64) ? ha[tok + (h & 1) * 64 + d]
                             : hb[tok + (h >> 1) * 64 + (d - 64)];
        hv[h][d] = val;
    }
    __syncthreads();
    int w = tid >> 6, lane = tid & 63;
    int half = lane >> 5, l5 = lane & 31;
    for (int it = 0; it < 16; ++it) {
        int i = w * 32 + it * 2 + half;
        float4 e = *(const float4*)(E + (size_t)i * 128 + l5 * 4);
        float acc[4];
        #pragma unroll
        for (int h = 0; h < 4; h++) {
            float4 x = *(const float4*)&hv[h][l5 * 4];
            acc[h] = e.x * x.x + e.y * x.y + e.z * x.z + e.w * x.w;
        }
        #pragma unroll
        for (int off = 1; off < 32; off <<= 1) {
            #pragma unroll
            for (int h = 0; h < 4; h++) acc[h] += __shfl_xor(acc[h], off);
        }
        if (l5 < 4) outl[l5][i] = acc[l5];
    }
    __syncthreads();
    if (tid < 128) {
        int h    = tid >> 5;
        int kcid = (tid >> 3) & 3;
        int s    = tid & 7;
        int shalf = s >> 2;
        int isLo  = s & 1;
        int jbase = ((s >> 1) & 1) * 8;
        int dbase = kcid * 32 + shalf * 16 + jbase;
        bf16x8 outv;
        #pragma unroll
        for (int j = 0; j < 8; j++) {
            float x = outl[h][dbase + j];
            short hh = to_bf16_rne(x);
            if (isLo) {
                float hf = __uint_as_float(((unsigned)(unsigned short)hh) << 16);
                outv[j] = to_bf16_rne(x - hf);
            } else {
                outv[j] = hh;
            }
        }
        int bh = b * NH + h;
        int row = tkn & 127;
        size_t base = ((((size_t)bh * 16 + (tkn >> 7)) * 4 + kcid) * 128 + row) * 64;
        *(bf16x8*)&rotS[base + (size_t)((s ^ (row & 7)) * 8)] = outv;
    }
}

// ---------------------------------------------------------------------------
// Score GEMM via split-bf16 MFMA + fused softmax partials (round-10 form:
// reg-based linear staging, direct S-store).
// ---------------------------------------------------------------------------
__global__ __launch_bounds__(256) void score_mfma_kernel(
    const short* __restrict__ qrotS, const short* __restrict__ krotS,
    const float* __restrict__ bias, const int* __restrict__ mask,
    float* __restrict__ attn, float* __restrict__ stats)
{
    __shared__ short lA[128 * 64];
    __shared__ short lB[128 * 64];
    __shared__ float redM[128][2];
    __shared__ float redS[128][2];

    int bid = blockIdx.x;                       // 4096
    int wg = (bid & 7) * 512 + (bid >> 3);      // XCD-chunked swizzle
    int bh = wg >> 8;
    int qt = (wg >> 4) & 15, st = wg & 15;
    int q0 = qt * 128, s0 = st * 128;
    int b = bh >> 2;

    int t = threadIdx.x;
    int l = t & 63, w = t >> 6;
    int wr = w >> 1, wc = w & 1;
    int lr = l & 15, kb = l >> 4;

    const short* Abase = qrotS + (((size_t)bh * 16 + qt) * 4) * 8192;
    const short* Bbase = krotS + (((size_t)bh * 16 + st) * 4) * 8192;

    f32x4 acc[4][4] = {};

    for (int kcid = 0; kcid < 4; kcid++) {
        {
            const bf16x8* srcA = (const bf16x8*)(Abase + (size_t)kcid * 8192) + t * 4;
            const bf16x8* srcB = (const bf16x8*)(Bbase + (size_t)kcid * 8192) + t * 4;
            bf16x8 a0 = srcA[0], a1 = srcA[1], a2 = srcA[2], a3 = srcA[3];
            bf16x8 b0 = srcB[0], b1 = srcB[1], b2 = srcB[2], b3 = srcB[3];
            bf16x8* dA = (bf16x8*)lA + t * 4;
            bf16x8* dB = (bf16x8*)lB + t * 4;
            dA[0] = a0; dA[1] = a1; dA[2] = a2; dA[3] = a3;
            dB[0] = b0; dB[1] = b1; dB[2] = b2; dB[3] = b3;
        }
        __syncthreads();

        bf16x8 ah[4], al[4], bhv[4], blv[4];
        #pragma unroll
        for (int m = 0; m < 4; m++) {
            int r = wr * 64 + m * 16 + lr;
            int r7 = r & 7, base = r * 64;
            ah[m] = *(bf16x8*)&lA[base + (((2 * kb + 0) ^ r7) * 8)];
            al[m] = *(bf16x8*)&lA[base + (((2 * kb + 1) ^ r7) * 8)];
        }
        #pragma unroll
        for (int n = 0; n < 4; n++) {
            int r = wc * 64 + n * 16 + lr;
            int r7 = r & 7, base = r * 64;
            bhv[n] = *(bf16x8*)&lB[base + (((2 * kb + 0) ^ r7) * 8)];
            blv[n] = *(bf16x8*)&lB[base + (((2 * kb + 1) ^ r7) * 8)];
        }
        #pragma unroll
        for (int m = 0; m < 4; m++) {
            #pragma unroll
            for (int n = 0; n < 4; n++) {
                acc[m][n] = __builtin_amdgcn_mfma_f32_16x16x32_bf16(ah[m], bhv[n], acc[m][n], 0, 0, 0);
                acc[m][n] = __builtin_amdgcn_mfma_f32_16x16x32_bf16(ah[m], blv[n], acc[m][n], 0, 0, 0);
                acc[m][n] = __builtin_amdgcn_mfma_f32_16x16x32_bf16(al[m], bhv[n], acc[m][n], 0, 0, 0);
            }
        }
        __syncthreads();
    }

    // ---- epilogue: finalize S in registers, write raw S ----
    const float scale = 0.08838834764831845f;   // 1/sqrt(128)
    #pragma unroll
    for (int n = 0; n < 4; n++) {
        int gs = s0 + wc * 64 + n * 16 + lr;
        float adj = -1e9f * (float)mask[b * SL + gs] - bias[b * SL + gs];
        #pragma unroll
        for (int m = 0; m < 4; m++) {
            int gq = q0 + wr * 64 + m * 16 + kb * 4;
            float* dst = attn + ((size_t)bh * QL + gq) * SL + gs;
            f32x4 c = acc[m][n];
            c[0] = c[0] * scale + adj;
            c[1] = c[1] * scale + adj;
            c[2] = c[2] * scale + adj;
            c[3] = c[3] * scale + adj;
            acc[m][n] = c;
            dst[0 * SL] = c[0];
            dst[1 * SL] = c[1];
            dst[2 * SL] = c[2];
            dst[3 * SL] = c[3];
        }
    }

    // ---- per-row tile max ----
    #pragma unroll
    for (int m = 0; m < 4; m++) {
        #pragma unroll
        for (int i = 0; i < 4; i++) {
            float rm = fmaxf(fmaxf(acc[m][0][i], acc[m][1][i]),
                             fmaxf(acc[m][2][i], acc[m][3][i]));
            rm = fmaxf(rm, __shfl_xor(rm, 1));
            rm = fmaxf(rm, __shfl_xor(rm, 2));
            rm = fmaxf(rm, __shfl_xor(rm, 4));
            rm = fmaxf(rm, __shfl_xor(rm, 8));
            if (lr == 0) redM[wr * 64 + m * 16 + kb * 4 + i][wc] = rm;
        }
    }
    __syncthreads();
    // ---- per-row tile expsum relative to combined tile max ----
    #pragma unroll
    for (int m = 0; m < 4; m++) {
        #pragma unroll
        for (int i = 0; i < 4; i++) {
            int row = wr * 64 + m * 16 + kb * 4 + i;
            float mt = fmaxf(redM[row][0], redM[row][1]);
            float es = __expf(acc[m][0][i] - mt) + __expf(acc[m][1][i] - mt)
                     + __expf(acc[m][2][i] - mt) + __expf(acc[m][3][i] - mt);
            es += __shfl_xor(es, 1);
            es += __shfl_xor(es, 2);
            es += __shfl_xor(es, 4);
            es += __shfl_xor(es, 8);
            if (lr == 0) redS[row][wc] = es;
        }
    }
    __syncthreads();
    if (t < 128) {
        float mt = fmaxf(redM[t][0], redM[t][1]);
        float es = redS[t][0] + redS[t][1];
        size_t r = (size_t)bh * QL + q0 + t;
        stats[(r * 16 + st) * 2 + 0] = mt;
        stats[(r * 16 + st) * 2 + 1] = es;
    }
}

// ---------------------------------------------------------------------------
// Flash combine: per row, 16 (max, expsum) partials -> rowmax, 1/rowsum.
// ---------------------------------------------------------------------------
__global__ __launch_bounds__(256) void sreduce_kernel(
    const float* __restrict__ stats,
    float* __restrict__ rowm, float* __restrict__ rowinv)
{
    int r = blockIdx.x * 256 + threadIdx.x;     // 32768 rows
    const float* src = stats + (size_t)r * 32;
    float4 p[8];
    #pragma unroll
    for (int j = 0; j < 8; j++) p[j] = *(const float4*)(src + j * 4);
    float m = -INFINITY;
    #pragma unroll
    for (int j = 0; j < 8; j++) { m = fmaxf(m, p[j].x); m = fmaxf(m, p[j].z); }
    float s = 0.f;
    #pragma unroll
    for (int j = 0; j < 8; j++) {
        s += p[j].y * __expf(p[j].x - m);
        s += p[j].w * __expf(p[j].z - m);
    }
    rowm[r] = m;
    rowinv[r] = 1.0f / s;
}

// ---------------------------------------------------------------------------
// V pre-transpose (unchanged, validated round 5)
// ---------------------------------------------------------------------------
__global__ __launch_bounds__(256) void vtrans_kernel(
    const float* __restrict__ va, const float* __restrict__ vb,
    short* __restrict__ vT)
{
    int sblk = blockIdx.x;                    // 64
    int bh = blockIdx.y;                      // 16
    int b = bh >> 2, h = bh & 3;
    int hao = (h & 1) * 64, hbo = (h >> 1) * 64;
    __shared__ float vt[32][132];
    int t = threadIdx.x;
    for (int f = t; f < 1024; f += 256) {
        int s = f >> 5, c4 = (f & 31) * 4;
        size_t tok = (size_t)(b * SL + sblk * 32 + s) * 128;
        float4 vv = (c4 < 64) ? *(const float4*)(va + tok + hao + c4)
                              : *(const float4*)(vb + tok + hbo + (c4 - 64));
        *(float4*)&vt[s][c4] = vv;
    }
    __syncthreads();
    int d = t >> 1, shalf = t & 1;
    bf16x8 hi[2], lo[2];
    #pragma unroll
    for (int kb2 = 0; kb2 < 2; kb2++) {
        int kb = shalf * 2 + kb2;
        #pragma unroll
        for (int j = 0; j < 8; j++) {
            float x = vt[kb * 8 + j][d];
            short hh = to_bf16_rne(x);
            float hf = __uint_as_float(((unsigned)(unsigned short)hh) << 16);
            hi[kb2][j] = hh;
            lo[kb2][j] = to_bf16_rne(x - hf);
        }
    }
    size_t base = (((size_t)bh * 64 + sblk) * 128 + d) * 64;
    int d7 = d & 7;
    *(bf16x8*)&vT[base + (size_t)(((2 * (shalf * 2 + 0) + 0) ^ d7) * 8)] = hi[0];
    *(bf16x8*)&vT[base + (size_t)(((2 * (shalf * 2 + 0) + 1) ^ d7) * 8)] = lo[0];
    *(bf16x8*)&vT[base + (size_t)(((2 * (shalf * 2 + 1) + 0) ^ d7) * 8)] = hi[1];
    *(bf16x8*)&vT[base + (size_t)(((2 * (shalf * 2 + 1) + 1) ^ d7) * 8)] = lo[1];
}

// ---------------------------------------------------------------------------
// Fused softmax+PV (round-10 form: reg-based staging)
// ---------------------------------------------------------------------------
__global__ __launch_bounds__(256) void pv_fused_kernel(
    float* __restrict__ attn, const short* __restrict__ vT,
    const float* __restrict__ rowm, const float* __restrict__ rowinv,
    float* __restrict__ outh)
{
    __shared__ short lA[128 * 64];
    __shared__ short lB[128 * 64];

    int bid = blockIdx.x;                     // 256
    int wg = (bid & 7) * 32 + (bid >> 3);     // XCD swizzle
    int bh = wg >> 4, qt = wg & 15;
    int q0 = qt * 128;

    float* Ag = attn + ((size_t)bh * QL + q0) * SL;
    const short* Bg = vT + (size_t)bh * 64 * 8192;

    int t = threadIdx.x;
    int srow = t >> 1, shalf = t & 1;
    int l = t & 63, w = t >> 6;
    int wr = w >> 1, wc = w & 1;
    int lr = l & 15, kb = l >> 4;

    float rm  = rowm[(size_t)bh * QL + q0 + srow];
    float riv = rowinv[(size_t)bh * QL + q0 + srow];

    f32x4 acc[4][4] = {};

    for (int sblk = 0; sblk < 64; sblk++) {
        {
            float* src = Ag + (size_t)srow * SL + sblk * 32 + shalf * 16;
            float x[16];
            #pragma unroll
            for (int j = 0; j < 4; j++)
                *(float4*)&x[j * 4] = *(const float4*)(src + j * 4);
            #pragma unroll
            for (int j = 0; j < 16; j++)
                x[j] = __expf(x[j] - rm) * riv;
            #pragma unroll
            for (int j = 0; j < 4; j++)
                *(float4*)(src + j * 4) = *(float4*)&x[j * 4];
            bf16x8 h0, l0, h1, l1;
            split8(&x[0], h0, l0);
            split8(&x[8], h1, l1);
            int base = srow * 64, r7 = srow & 7;
            *(bf16x8*)&lA[base + (((4 * shalf + 0) ^ r7) * 8)] = h0;
            *(bf16x8*)&lA[base + (((4 * shalf + 1) ^ r7) * 8)] = l0;
            *(bf16x8*)&lA[base + (((4 * shalf + 2) ^ r7) * 8)] = h1;
            *(bf16x8*)&lA[base + (((4 * shalf + 3) ^ r7) * 8)] = l1;
        }
        {
            const bf16x8* src = (const bf16x8*)(Bg + (size_t)sblk * 8192) + t * 4;
            bf16x8 v0 = src[0], v1 = src[1], v2 = src[2], v3 = src[3];
            bf16x8* dst = (bf16x8*)lB + t * 4;
            dst[0] = v0; dst[1] = v1; dst[2] = v2; dst[3] = v3;
        }
        __syncthreads();

        bf16x8 ah[4], al[4], bhv[4], blv[4];
        #pragma unroll
        for (int m = 0; m < 4; m++) {
            int r = wr * 64 + m * 16 + lr;
            int r7 = r & 7, base = r * 64;
            ah[m] = *(bf16x8*)&lA[base + (((2 * kb + 0) ^ r7) * 8)];
            al[m] = *(bf16x8*)&lA[base + (((2 * kb + 1) ^ r7) * 8)];
        }
        #pragma unroll
        for (int n = 0; n < 4; n++) {
            int r = wc * 64 + n * 16 + lr;
            int r7 = r & 7, base = r * 64;
            bhv[n] = *(bf16x8*)&lB[base + (((2 * kb + 0) ^ r7) * 8)];
            blv[n] = *(bf16x8*)&lB[base + (((2 * kb + 1) ^ r7) * 8)];
        }
        #pragma unroll
        for (int m = 0; m < 4; m++) {
            #pragma unroll
            for (int n = 0; n < 4; n++) {
                acc[m][n] = __builtin_amdgcn_mfma_f32_16x16x32_bf16(ah[m], bhv[n], acc[m][n], 0, 0, 0);
                acc[m][n] = __builtin_amdgcn_mfma_f32_16x16x32_bf16(ah[m], blv[n], acc[m][n], 0, 0, 0);
                acc[m][n] = __builtin_amdgcn_mfma_f32_16x16x32_bf16(al[m], bhv[n], acc[m][n], 0, 0, 0);
            }
        }
        __syncthreads();
    }

    #pragma unroll
    for (int n = 0; n < 4; n++) {
        int gd = wc * 64 + n * 16 + lr;
        #pragma unroll
        for (int m = 0; m < 4; m++) {
            int gq = q0 + wr * 64 + m * 16 + kb * 4;
            float* dst = outh + ((size_t)bh * QL + gq) * 128 + gd;
            f32x4 c = acc[m][n];
            dst[0 * 128] = c[0];
            dst[1 * 128] = c[1];
            dst[2 * 128] = c[2];
            dst[3 * 128] = c[3];
        }
    }
}

// ---------------------------------------------------------------------------
// Output projection via split-bf16 MFMA, 2-way split-K for 2 blocks/CU.
// z = sel*2 + ks; block covers K chunk [ks*128, ks*128+128); partial to opart.
// ---------------------------------------------------------------------------
__global__ __launch_bounds__(256) void oproj_mfma_kernel(
    const float* __restrict__ outh, const float* __restrict__ Woa, const float* __restrict__ Wob,
    float* __restrict__ opart)
{
    int bt = blockIdx.x;                  // 64 = 4 b * 16 t-tiles
    int b = bt >> 4, tt = bt & 15;
    int t0 = tt * 128;
    int n0 = blockIdx.y * 128;
    int sel = blockIdx.z >> 1;
    int ks  = blockIdx.z & 1;
    const float* W = sel ? Wob : Woa;
    int doff = sel ? 64 : 0;

    __shared__ short lA[128 * 64];
    __shared__ short lB[128 * 64];

    int t = threadIdx.x;
    int srow = t >> 1, shalf = t & 1;
    int l = t & 63, w = t >> 6;
    int wr = w >> 1, wc = w & 1;
    int lr = l & 15, kb = l >> 4;

    f32x4 acc[4][4] = {};

    for (int kc = ks * 128; kc < ks * 128 + 128; kc += 32) {
        {
            int k0 = kc + shalf * 16;
            int h = k0 >> 6, d0 = k0 & 63;
            const float* srcA = outh + ((size_t)(b * NH + h) * QL + t0 + srow) * 128 + doff + d0;
            float xa[16];
            #pragma unroll
            for (int j = 0; j < 4; j++)
                *(float4*)&xa[j * 4] = *(const float4*)(srcA + j * 4);
            bf16x8 h0, l0, h1, l1;
            split8(&xa[0], h0, l0);
            split8(&xa[8], h1, l1);
            int base = srow * 64, r7 = srow & 7;
            *(bf16x8*)&lA[base + (((4 * shalf + 0) ^ r7) * 8)] = h0;
            *(bf16x8*)&lA[base + (((4 * shalf + 1) ^ r7) * 8)] = l0;
            *(bf16x8*)&lA[base + (((4 * shalf + 2) ^ r7) * 8)] = h1;
            *(bf16x8*)&lA[base + (((4 * shalf + 3) ^ r7) * 8)] = l1;
        }
        {
            int ncol = srow;
            float xb[16];
            #pragma unroll
            for (int j = 0; j < 16; j++)
                xb[j] = W[(size_t)(kc + shalf * 16 + j) * 256 + n0 + ncol];
            bf16x8 h0, l0, h1, l1;
            split8(&xb[0], h0, l0);
            split8(&xb[8], h1, l1);
            int base = ncol * 64, r7 = ncol & 7;
            *(bf16x8*)&lB[base + (((4 * shalf + 0) ^ r7) * 8)] = h0;
            *(bf16x8*)&lB[base + (((4 * shalf + 1) ^ r7) * 8)] = l0;
            *(bf16x8*)&lB[base + (((4 * shalf + 2) ^ r7) * 8)] = h1;
            *(bf16x8*)&lB[base + (((4 * shalf + 3) ^ r7) * 8)] = l1;
        }
        __syncthreads();

        bf16x8 ah[4], al[4], bhv[4], blv[4];
        #pragma unroll
        for (int m = 0; m < 4; m++) {
            int r = wr * 64 + m * 16 + lr;
            int r7 = r & 7, base = r * 64;
            ah[m] = *(bf16x8*)&lA[base + (((2 * kb + 0) ^ r7) * 8)];
            al[m] = *(bf16x8*)&lA[base + (((2 * kb + 1) ^ r7) * 8)];
        }
        #pragma unroll
        for (int n = 0; n < 4; n++) {
            int r = wc * 64 + n * 16 + lr;
            int r7 = r & 7, base = r * 64;
            bhv[n] = *(bf16x8*)&lB[base + (((2 * kb + 0) ^ r7) * 8)];
            blv[n] = *(bf16x8*)&lB[base + (((2 * kb + 1) ^ r7) * 8)];
        }
        #pragma unroll
        for (int m = 0; m < 4; m++) {
            #pragma unroll
            for (int n = 0; n < 4; n++) {
                acc[m][n] = __builtin_amdgcn_mfma_f32_16x16x32_bf16(ah[m], bhv[n], acc[m][n], 0, 0, 0);
                acc[m][n] = __builtin_amdgcn_mfma_f32_16x16x32_bf16(ah[m], blv[n], acc[m][n], 0, 0, 0);
                acc[m][n] = __builtin_amdgcn_mfma_f32_16x16x32_bf16(al[m], bhv[n], acc[m][n], 0, 0, 0);
            }
        }
        __syncthreads();
    }

    float* dstbase = opart + (size_t)ks * OSZ;
    #pragma unroll
    for (int n = 0; n < 4; n++) {
        int gcol = n0 + wc * 64 + n * 16 + lr;
        #pragma unroll
        for (int m = 0; m < 4; m++) {
            int grow = t0 + wr * 64 + m * 16 + kb * 4;
            float* dst = dstbase + ((size_t)((sel * BS + b) * QL) + grow) * 256 + gcol;
            f32x4 c = acc[m][n];
            dst[0 * 256] = c[0];
            dst[1 * 256] = c[1];
            dst[2 * 256] = c[2];
            dst[3 * 256] = c[3];
        }
    }
}

// ---------------------------------------------------------------------------
// Sum the 2 oproj split-K partials into the final output.
// ---------------------------------------------------------------------------
__global__ __launch_bounds__(256) void oadd_kernel(
    const float* __restrict__ opart, float* __restrict__ outp)
{
    size_t i = ((size_t)blockIdx.x * 256 + threadIdx.x) * 4;   // 4096 blocks cover OSZ
    float4 a = *(const float4*)(opart + i);
    float4 b = *(const float4*)(opart + OSZ + i);
    float4 o = make_float4(a.x + b.x, a.y + b.y, a.z + b.z, a.w + b.w);
    *(float4*)(outp + i) = o;
}

extern "C" void kernel_launch(void* const* d_in, const int* in_sizes, int n_in,
                              void* d_out, int out_size, void* d_ws, size_t ws_size,
                              hipStream_t stream)
{
    const float* q    = (const float*)d_in[0];
    const float* k    = (const float*)d_in[1];
    const float* v    = (const float*)d_in[2];
    const float* qse  = (const float*)d_in[3];
    const float* kvse = (const float*)d_in[4];
    const float* bias = (const float*)d_in[5];
    const int*   mask = (const int*)d_in[6];
    const float* Wqa  = (const float*)d_in[7];
    const float* Wqb  = (const float*)d_in[8];
    const float* Wka  = (const float*)d_in[9];
    const float* Wkb  = (const float*)d_in[10];
    const float* Wva  = (const float*)d_in[11];
    const float* Wvb  = (const float*)d_in[12];
    const float* Woa  = (const float*)d_in[13];
    const float* Wob  = (const float*)d_in[14];

    float* outp = (float*)d_out;
    float* attn = outp + OSZ;                  // attn region of d_out

    float* ws     = (float*)d_ws;
    float* qa     = ws + 0 * FSZ;
    float* qb     = ws + 1 * FSZ;
    float* ka     = ws + 2 * FSZ;
    float* kb     = ws + 3 * FSZ;
    float* va     = ws + 4 * FSZ;
    float* vb     = ws + 5 * FSZ;
    short* qrotS  = (short*)(ws + 6 * FSZ);    // 16.8 MB
    short* krotS  = (short*)(ws + 10 * FSZ);   // 16.8 MB
    float* stats  = ws + 14 * FSZ;             // 4 MB
    float* rowm   = ws + 15 * FSZ;             // 32768 floats
    float* rowinv = ws + 15 * FSZ + 32768;     // 32768 floats
    short* vT     = (short*)(ws + 16 * FSZ);   // 16.8 MB
    float* outh   = ws + 20 * FSZ;             // 16 MB
    float* opart  = ws + 24 * FSZ;             // 2 x OSZ = 33.6 MB

    proj_mfma_kernel<<<dim3(64, 6), 256, 0, stream>>>(q, k, v, Wqa, Wqb, Wka, Wkb, Wva, Wvb, ws);
    vtrans_kernel<<<dim3(64, 16), 256, 0, stream>>>(va, vb, vT);
    rot_split_kernel<<<dim3(QL, BS, 2), 256, 0, stream>>>(qa, qb, ka, kb, qse, kvse, qrotS, krotS);
    score_mfma_kernel<<<4096, 256, 0, stream>>>(qrotS, krotS, bias, mask, attn, stats);
    sreduce_kernel<<<128, 256, 0, stream>>>(stats, rowm, rowinv);
    pv_fused_kernel<<<256, 256, 0, stream>>>(attn, vT, rowm, rowinv, outh);
    oproj_mfma_kernel<<<dim3(64, 2, 4), 256, 0, stream>>>(outh, Woa, Wob, opart);
    oadd_kernel<<<4096, 256, 0, stream>>>(opart, outp);
}

// Round 15
// 610.206 us; speedup vs baseline: 1.0518x; 1.0133x over previous
//
#include <hip/hip_runtime.h>
#include <math.h>

#define QL 2048
#define SL 2048
#define BS 4
#define NH 4
#define FSZ ((size_t)BS * QL * 128)   // 1,048,576 floats = 4 MB
#define OSZ ((size_t)2 * BS * QL * 256)  // 4,194,304 floats

typedef short bf16x8 __attribute__((ext_vector_type(8)));
typedef float f32x4 __attribute__((ext_vector_type(4)));

__device__ __forceinline__ short to_bf16_rne(float x) {
    unsigned u = __float_as_uint(x);
    unsigned r = u + 0x7fffu + ((u >> 16) & 1u);
    return (short)(r >> 16);
}

__device__ __forceinline__ void split8(const float* x, bf16x8& hi, bf16x8& lo) {
    #pragma unroll
    for (int j = 0; j < 8; j++) {
        short hh = to_bf16_rne(x[j]);
        float hf = __uint_as_float(((unsigned)(unsigned short)hh) << 16);
        hi[j] = hh;
        lo[j] = to_bf16_rne(x[j] - hf);
    }
}

// ---------------------------------------------------------------------------
// Projection GEMM via split-bf16 MFMA (validated round 10)
// ---------------------------------------------------------------------------
__global__ __launch_bounds__(256) void proj_mfma_kernel(
    const float* __restrict__ q, const float* __restrict__ k, const float* __restrict__ v,
    const float* __restrict__ Wqa, const float* __restrict__ Wqb,
    const float* __restrict__ Wka, const float* __restrict__ Wkb,
    const float* __restrict__ Wva, const float* __restrict__ Wvb,
    float* __restrict__ ws)
{
    int id = blockIdx.y;
    const float* X; const float* W;
    const size_t HALF = (size_t)BS * QL * 256;
    switch (id) {
      case 0: X = q;        W = Wqa; break;
      case 1: X = q + HALF; W = Wqb; break;
      case 2: X = k;        W = Wka; break;
      case 3: X = k + HALF; W = Wkb; break;
      case 4: X = v;        W = Wva; break;
      default:X = v + HALF; W = Wvb; break;
    }
    float* Y = ws + (size_t)id * FSZ;
    int m0 = blockIdx.x * 128;

    __shared__ short lA[128 * 64];
    __shared__ short lB[128 * 64];

    int t = threadIdx.x;
    int srow = t >> 1, shalf = t & 1;
    int l = t & 63, w = t >> 6;
    int wr = w >> 1, wc = w & 1;
    int lr = l & 15, kb = l >> 4;

    f32x4 acc[4][4] = {};

    for (int kc = 0; kc < 256; kc += 32) {
        {
            const float* srcA = X + (size_t)(m0 + srow) * 256 + kc + shalf * 16;
            float xa[16];
            #pragma unroll
            for (int j = 0; j < 4; j++)
                *(float4*)&xa[j * 4] = *(const float4*)(srcA + j * 4);
            bf16x8 h0, l0, h1, l1;
            split8(&xa[0], h0, l0);
            split8(&xa[8], h1, l1);
            int base = srow * 64, r7 = srow & 7;
            *(bf16x8*)&lA[base + (((4 * shalf + 0) ^ r7) * 8)] = h0;
            *(bf16x8*)&lA[base + (((4 * shalf + 1) ^ r7) * 8)] = l0;
            *(bf16x8*)&lA[base + (((4 * shalf + 2) ^ r7) * 8)] = h1;
            *(bf16x8*)&lA[base + (((4 * shalf + 3) ^ r7) * 8)] = l1;
        }
        {
            int ncol = srow;
            float xb[16];
            #pragma unroll
            for (int j = 0; j < 16; j++)
                xb[j] = W[(size_t)(kc + shalf * 16 + j) * 128 + ncol];
            bf16x8 h0, l0, h1, l1;
            split8(&xb[0], h0, l0);
            split8(&xb[8], h1, l1);
            int base = ncol * 64, r7 = ncol & 7;
            *(bf16x8*)&lB[base + (((4 * shalf + 0) ^ r7) * 8)] = h0;
            *(bf16x8*)&lB[base + (((4 * shalf + 1) ^ r7) * 8)] = l0;
            *(bf16x8*)&lB[base + (((4 * shalf + 2) ^ r7) * 8)] = h1;
            *(bf16x8*)&lB[base + (((4 * shalf + 3) ^ r7) * 8)] = l1;
        }
        __syncthreads();

        bf16x8 ah[4], al[4], bhv[4], blv[4];
        #pragma unroll
        for (int m = 0; m < 4; m++) {
            int r = wr * 64 + m * 16 + lr;
            int r7 = r & 7, base = r * 64;
            ah[m] = *(bf16x8*)&lA[base + (((2 * kb + 0) ^ r7) * 8)];
            al[m] = *(bf16x8*)&lA[base + (((2 * kb + 1) ^ r7) * 8)];
        }
        #pragma unroll
        for (int n = 0; n < 4; n++) {
            int r = wc * 64 + n * 16 + lr;
            int r7 = r & 7, base = r * 64;
            bhv[n] = *(bf16x8*)&lB[base + (((2 * kb + 0) ^ r7) * 8)];
            blv[n] = *(bf16x8*)&lB[base + (((2 * kb + 1) ^ r7) * 8)];
        }
        #pragma unroll
        for (int m = 0; m < 4; m++) {
            #pragma unroll
            for (int n = 0; n < 4; n++) {
                acc[m][n] = __builtin_amdgcn_mfma_f32_16x16x32_bf16(ah[m], bhv[n], acc[m][n], 0, 0, 0);
                acc[m][n] = __builtin_amdgcn_mfma_f32_16x16x32_bf16(ah[m], blv[n], acc[m][n], 0, 0, 0);
                acc[m][n] = __builtin_amdgcn_mfma_f32_16x16x32_bf16(al[m], bhv[n], acc[m][n], 0, 0, 0);
            }
        }
        __syncthreads();
    }

    #pragma unroll
    for (int n = 0; n < 4; n++) {
        int gcol = wc * 64 + n * 16 + lr;
        #pragma unroll
        for (int m = 0; m < 4; m++) {
            int grow = m0 + wr * 64 + m * 16 + kb * 4;
            float* dst = Y + (size_t)grow * 128 + gcol;
            f32x4 c = acc[m][n];
            dst[0 * 128] = c[0];
            dst[1 * 128] = c[1];
            dst[2 * 128] = c[2];
            dst[3 * 128] = c[3];
        }
    }
}

// ---------------------------------------------------------------------------
// Spatial rotation -> split-bf16 pre-swizzled planes; z selects q vs kv.
// ---------------------------------------------------------------------------
__global__ __launch_bounds__(256) void rot_split_kernel(
    const float* __restrict__ qa, const float* __restrict__ qb,
    const float* __restrict__ ka, const float* __restrict__ kb,
    const float* __restrict__ qse, const float* __restrict__ kvse,
    short* __restrict__ qrotS, short* __restrict__ krotS)
{
    int tkn = blockIdx.x;
    int b = blockIdx.y;
    int z = blockIdx.z;                       // 0 = q, 1 = kv
    const float* ha = z ? ka : qa;
    const float* hb = z ? kb : qb;
    const float* E = z ? (kvse + (size_t)(b * SL + tkn) * 16384)
                       : (qse + (size_t)b * 16384);
    short* rotS = z ? krotS : qrotS;

    __shared__ float hv[4][128];
    __shared__ float outl[4][128];
    int tid = threadIdx.x;
    size_t tok = (size_t)(b * QL + tkn) * 128;
    for (int idx = tid; idx < 512; idx += 256) {
        int h = idx >> 7, d = idx & 127;
        float val = (d < 64) ? ha[tok + (h & 1) * 64 + d]
                             : hb[tok + (h >> 1) * 64 + (d - 64)];
        hv[h][d] = val;
    }
    __syncthreads();
    int w = tid >> 6, lane = tid & 63;
    int half = lane >> 5, l5 = lane & 31;
    for (int it = 0; it < 16; ++it) {
        int i = w * 32 + it * 2 + half;
        float4 e = *(const float4*)(E + (size_t)i * 128 + l5 * 4);
        float acc[4];
        #pragma unroll
        for (int h = 0; h < 4; h++) {
            float4 x = *(const float4*)&hv[h][l5 * 4];
            acc[h] = e.x * x.x + e.y * x.y + e.z * x.z + e.w * x.w;
        }
        #pragma unroll
        for (int off = 1; off < 32; off <<= 1) {
            #pragma unroll
            for (int h = 0; h < 4; h++) acc[h] += __shfl_xor(acc[h], off);
        }
        if (l5 < 4) outl[l5][i] = acc[l5];
    }
    __syncthreads();
    if (tid < 128) {
        int h    = tid >> 5;
        int kcid = (tid >> 3) & 3;
        int s    = tid & 7;
        int shalf = s >> 2;
        int isLo  = s & 1;
        int jbase = ((s >> 1) & 1) * 8;
        int dbase = kcid * 32 + shalf * 16 + jbase;
        bf16x8 outv;
        #pragma unroll
        for (int j = 0; j < 8; j++) {
            float x = outl[h][dbase + j];
            short hh = to_bf16_rne(x);
            if (isLo) {
                float hf = __uint_as_float(((unsigned)(unsigned short)hh) << 16);
                outv[j] = to_bf16_rne(x - hf);
            } else {
                outv[j] = hh;
            }
        }
        int bh = b * NH + h;
        int row = tkn & 127;
        size_t base = ((((size_t)bh * 16 + (tkn >> 7)) * 4 + kcid) * 128 + row) * 64;
        *(bf16x8*)&rotS[base + (size_t)((s ^ (row & 7)) * 8)] = outv;
    }
}

// ---------------------------------------------------------------------------
// Score GEMM via split-bf16 MFMA + fused softmax partials (validated R10 form)
// ---------------------------------------------------------------------------
__global__ __launch_bounds__(256) void score_mfma_kernel(
    const short* __restrict__ qrotS, const short* __restrict__ krotS,
    const float* __restrict__ bias, const int* __restrict__ mask,
    float* __restrict__ attn, float* __restrict__ stats)
{
    __shared__ short lA[128 * 64];
    __shared__ short lB[128 * 64];
    __shared__ float redM[128][2];
    __shared__ float redS[128][2];

    int bid = blockIdx.x;                       // 4096
    int wg = (bid & 7) * 512 + (bid >> 3);      // XCD-chunked swizzle
    int bh = wg >> 8;
    int qt = (wg >> 4) & 15, st = wg & 15;
    int q0 = qt * 128, s0 = st * 128;
    int b = bh >> 2;

    int t = threadIdx.x;
    int l = t & 63, w = t >> 6;
    int wr = w >> 1, wc = w & 1;
    int lr = l & 15, kb = l >> 4;

    const short* Abase = qrotS + (((size_t)bh * 16 + qt) * 4) * 8192;
    const short* Bbase = krotS + (((size_t)bh * 16 + st) * 4) * 8192;

    f32x4 acc[4][4] = {};

    for (int kcid = 0; kcid < 4; kcid++) {
        {
            const bf16x8* srcA = (const bf16x8*)(Abase + (size_t)kcid * 8192) + t * 4;
            const bf16x8* srcB = (const bf16x8*)(Bbase + (size_t)kcid * 8192) + t * 4;
            bf16x8 a0 = srcA[0], a1 = srcA[1], a2 = srcA[2], a3 = srcA[3];
            bf16x8 b0 = srcB[0], b1 = srcB[1], b2 = srcB[2], b3 = srcB[3];
            bf16x8* dA = (bf16x8*)lA + t * 4;
            bf16x8* dB = (bf16x8*)lB + t * 4;
            dA[0] = a0; dA[1] = a1; dA[2] = a2; dA[3] = a3;
            dB[0] = b0; dB[1] = b1; dB[2] = b2; dB[3] = b3;
        }
        __syncthreads();

        bf16x8 ah[4], al[4], bhv[4], blv[4];
        #pragma unroll
        for (int m = 0; m < 4; m++) {
            int r = wr * 64 + m * 16 + lr;
            int r7 = r & 7, base = r * 64;
            ah[m] = *(bf16x8*)&lA[base + (((2 * kb + 0) ^ r7) * 8)];
            al[m] = *(bf16x8*)&lA[base + (((2 * kb + 1) ^ r7) * 8)];
        }
        #pragma unroll
        for (int n = 0; n < 4; n++) {
            int r = wc * 64 + n * 16 + lr;
            int r7 = r & 7, base = r * 64;
            bhv[n] = *(bf16x8*)&lB[base + (((2 * kb + 0) ^ r7) * 8)];
            blv[n] = *(bf16x8*)&lB[base + (((2 * kb + 1) ^ r7) * 8)];
        }
        #pragma unroll
        for (int m = 0; m < 4; m++) {
            #pragma unroll
            for (int n = 0; n < 4; n++) {
                acc[m][n] = __builtin_amdgcn_mfma_f32_16x16x32_bf16(ah[m], bhv[n], acc[m][n], 0, 0, 0);
                acc[m][n] = __builtin_amdgcn_mfma_f32_16x16x32_bf16(ah[m], blv[n], acc[m][n], 0, 0, 0);
                acc[m][n] = __builtin_amdgcn_mfma_f32_16x16x32_bf16(al[m], bhv[n], acc[m][n], 0, 0, 0);
            }
        }
        __syncthreads();
    }

    // ---- epilogue: finalize S in registers, write raw S ----
    const float scale = 0.08838834764831845f;   // 1/sqrt(128)
    #pragma unroll
    for (int n = 0; n < 4; n++) {
        int gs = s0 + wc * 64 + n * 16 + lr;
        float adj = -1e9f * (float)mask[b * SL + gs] - bias[b * SL + gs];
        #pragma unroll
        for (int m = 0; m < 4; m++) {
            int gq = q0 + wr * 64 + m * 16 + kb * 4;
            float* dst = attn + ((size_t)bh * QL + gq) * SL + gs;
            f32x4 c = acc[m][n];
            c[0] = c[0] * scale + adj;
            c[1] = c[1] * scale + adj;
            c[2] = c[2] * scale + adj;
            c[3] = c[3] * scale + adj;
            acc[m][n] = c;
            dst[0 * SL] = c[0];
            dst[1 * SL] = c[1];
            dst[2 * SL] = c[2];
            dst[3 * SL] = c[3];
        }
    }

    // ---- per-row tile max ----
    #pragma unroll
    for (int m = 0; m < 4; m++) {
        #pragma unroll
        for (int i = 0; i < 4; i++) {
            float rm = fmaxf(fmaxf(acc[m][0][i], acc[m][1][i]),
                             fmaxf(acc[m][2][i], acc[m][3][i]));
            rm = fmaxf(rm, __shfl_xor(rm, 1));
            rm = fmaxf(rm, __shfl_xor(rm, 2));
            rm = fmaxf(rm, __shfl_xor(rm, 4));
            rm = fmaxf(rm, __shfl_xor(rm, 8));
            if (lr == 0) redM[wr * 64 + m * 16 + kb * 4 + i][wc] = rm;
        }
    }
    __syncthreads();
    // ---- per-row tile expsum relative to combined tile max ----
    #pragma unroll
    for (int m = 0; m < 4; m++) {
        #pragma unroll
        for (int i = 0; i < 4; i++) {
            int row = wr * 64 + m * 16 + kb * 4 + i;
            float mt = fmaxf(redM[row][0], redM[row][1]);
            float es = __expf(acc[m][0][i] - mt) + __expf(acc[m][1][i] - mt)
                     + __expf(acc[m][2][i] - mt) + __expf(acc[m][3][i] - mt);
            es += __shfl_xor(es, 1);
            es += __shfl_xor(es, 2);
            es += __shfl_xor(es, 4);
            es += __shfl_xor(es, 8);
            if (lr == 0) redS[row][wc] = es;
        }
    }
    __syncthreads();
    if (t < 128) {
        float mt = fmaxf(redM[t][0], redM[t][1]);
        float es = redS[t][0] + redS[t][1];
        size_t r = (size_t)bh * QL + q0 + t;
        stats[(r * 16 + st) * 2 + 0] = mt;
        stats[(r * 16 + st) * 2 + 1] = es;
    }
}

// ---------------------------------------------------------------------------
// V pre-transpose (unchanged, validated round 5)
// ---------------------------------------------------------------------------
__global__ __launch_bounds__(256) void vtrans_kernel(
    const float* __restrict__ va, const float* __restrict__ vb,
    short* __restrict__ vT)
{
    int sblk = blockIdx.x;                    // 64
    int bh = blockIdx.y;                      // 16
    int b = bh >> 2, h = bh & 3;
    int hao = (h & 1) * 64, hbo = (h >> 1) * 64;
    __shared__ float vt[32][132];
    int t = threadIdx.x;
    for (int f = t; f < 1024; f += 256) {
        int s = f >> 5, c4 = (f & 31) * 4;
        size_t tok = (size_t)(b * SL + sblk * 32 + s) * 128;
        float4 vv = (c4 < 64) ? *(const float4*)(va + tok + hao + c4)
                              : *(const float4*)(vb + tok + hbo + (c4 - 64));
        *(float4*)&vt[s][c4] = vv;
    }
    __syncthreads();
    int d = t >> 1, shalf = t & 1;
    bf16x8 hi[2], lo[2];
    #pragma unroll
    for (int kb2 = 0; kb2 < 2; kb2++) {
        int kb = shalf * 2 + kb2;
        #pragma unroll
        for (int j = 0; j < 8; j++) {
            float x = vt[kb * 8 + j][d];
            short hh = to_bf16_rne(x);
            float hf = __uint_as_float(((unsigned)(unsigned short)hh) << 16);
            hi[kb2][j] = hh;
            lo[kb2][j] = to_bf16_rne(x - hf);
        }
    }
    size_t base = (((size_t)bh * 64 + sblk) * 128 + d) * 64;
    int d7 = d & 7;
    *(bf16x8*)&vT[base + (size_t)(((2 * (shalf * 2 + 0) + 0) ^ d7) * 8)] = hi[0];
    *(bf16x8*)&vT[base + (size_t)(((2 * (shalf * 2 + 0) + 1) ^ d7) * 8)] = lo[0];
    *(bf16x8*)&vT[base + (size_t)(((2 * (shalf * 2 + 1) + 0) ^ d7) * 8)] = hi[1];
    *(bf16x8*)&vT[base + (size_t)(((2 * (shalf * 2 + 1) + 1) ^ d7) * 8)] = lo[1];
}

// ---------------------------------------------------------------------------
// Fused softmax+PV with in-kernel stats combine and S-load register
// double-buffering. 256 blocks, 128q x 128d tile.
// ---------------------------------------------------------------------------
__global__ __launch_bounds__(256) void pv_fused_kernel(
    float* __restrict__ attn, const short* __restrict__ vT,
    const float* __restrict__ stats,
    float* __restrict__ outh)
{
    __shared__ short lA[128 * 64];
    __shared__ short lB[128 * 64];
    __shared__ float lrm[128];
    __shared__ float lriv[128];

    int bid = blockIdx.x;                     // 256
    int wg = (bid & 7) * 32 + (bid >> 3);     // XCD swizzle
    int bh = wg >> 4, qt = wg & 15;
    int q0 = qt * 128;

    float* Ag = attn + ((size_t)bh * QL + q0) * SL;
    const short* Bg = vT + (size_t)bh * 64 * 8192;

    int t = threadIdx.x;
    int srow = t >> 1, shalf = t & 1;
    int l = t & 63, w = t >> 6;
    int wr = w >> 1, wc = w & 1;
    int lr = l & 15, kb = l >> 4;

    // ---- stats combine (was sreduce_kernel): one row per thread t<128 ----
    if (t < 128) {
        const float* src = stats + ((size_t)bh * QL + q0 + t) * 32;
        float4 p[8];
        #pragma unroll
        for (int j = 0; j < 8; j++) p[j] = *(const float4*)(src + j * 4);
        float m = -INFINITY;
        #pragma unroll
        for (int j = 0; j < 8; j++) { m = fmaxf(m, p[j].x); m = fmaxf(m, p[j].z); }
        float s = 0.f;
        #pragma unroll
        for (int j = 0; j < 8; j++) {
            s += p[j].y * __expf(p[j].x - m);
            s += p[j].w * __expf(p[j].z - m);
        }
        lrm[t] = m;
        lriv[t] = 1.0f / s;
    }
    __syncthreads();
    float rm  = lrm[srow];
    float riv = lriv[srow];

    f32x4 acc[4][4] = {};

    // prologue: load sblk 0's S chunk
    float4 xq0, xq1, xq2, xq3;
    {
        const float* src = Ag + (size_t)srow * SL + 0 + shalf * 16;
        xq0 = *(const float4*)(src + 0);
        xq1 = *(const float4*)(src + 4);
        xq2 = *(const float4*)(src + 8);
        xq3 = *(const float4*)(src + 12);
    }

    for (int sblk = 0; sblk < 64; sblk++) {
        // prefetch next sblk's S chunk (issues before current's VALU work)
        float4 xn0, xn1, xn2, xn3;
        if (sblk < 63) {
            const float* srcn = Ag + (size_t)srow * SL + (sblk + 1) * 32 + shalf * 16;
            xn0 = *(const float4*)(srcn + 0);
            xn1 = *(const float4*)(srcn + 4);
            xn2 = *(const float4*)(srcn + 8);
            xn3 = *(const float4*)(srcn + 12);
        }
        // stage A: current S -> P = exp(S-m)*inv; write P back; split hi/lo
        {
            float x[16];
            *(float4*)&x[0]  = xq0;
            *(float4*)&x[4]  = xq1;
            *(float4*)&x[8]  = xq2;
            *(float4*)&x[12] = xq3;
            #pragma unroll
            for (int j = 0; j < 16; j++)
                x[j] = __expf(x[j] - rm) * riv;
            float* src = Ag + (size_t)srow * SL + sblk * 32 + shalf * 16;
            #pragma unroll
            for (int j = 0; j < 4; j++)
                *(float4*)(src + j * 4) = *(float4*)&x[j * 4];
            bf16x8 h0, l0, h1, l1;
            split8(&x[0], h0, l0);
            split8(&x[8], h1, l1);
            int base = srow * 64, r7 = srow & 7;
            *(bf16x8*)&lA[base + (((4 * shalf + 0) ^ r7) * 8)] = h0;
            *(bf16x8*)&lA[base + (((4 * shalf + 1) ^ r7) * 8)] = l0;
            *(bf16x8*)&lA[base + (((4 * shalf + 2) ^ r7) * 8)] = h1;
            *(bf16x8*)&lA[base + (((4 * shalf + 3) ^ r7) * 8)] = l1;
        }
        // stage B: linear 16 KB copy of pre-swizzled bytes
        {
            const bf16x8* src = (const bf16x8*)(Bg + (size_t)sblk * 8192) + t * 4;
            bf16x8 v0 = src[0], v1 = src[1], v2 = src[2], v3 = src[3];
            bf16x8* dst = (bf16x8*)lB + t * 4;
            dst[0] = v0; dst[1] = v1; dst[2] = v2; dst[3] = v3;
        }
        __syncthreads();

        bf16x8 ah[4], al[4], bhv[4], blv[4];
        #pragma unroll
        for (int m = 0; m < 4; m++) {
            int r = wr * 64 + m * 16 + lr;
            int r7 = r & 7, base = r * 64;
            ah[m] = *(bf16x8*)&lA[base + (((2 * kb + 0) ^ r7) * 8)];
            al[m] = *(bf16x8*)&lA[base + (((2 * kb + 1) ^ r7) * 8)];
        }
        #pragma unroll
        for (int n = 0; n < 4; n++) {
            int r = wc * 64 + n * 16 + lr;
            int r7 = r & 7, base = r * 64;
            bhv[n] = *(bf16x8*)&lB[base + (((2 * kb + 0) ^ r7) * 8)];
            blv[n] = *(bf16x8*)&lB[base + (((2 * kb + 1) ^ r7) * 8)];
        }
        #pragma unroll
        for (int m = 0; m < 4; m++) {
            #pragma unroll
            for (int n = 0; n < 4; n++) {
                acc[m][n] = __builtin_amdgcn_mfma_f32_16x16x32_bf16(ah[m], bhv[n], acc[m][n], 0, 0, 0);
                acc[m][n] = __builtin_amdgcn_mfma_f32_16x16x32_bf16(ah[m], blv[n], acc[m][n], 0, 0, 0);
                acc[m][n] = __builtin_amdgcn_mfma_f32_16x16x32_bf16(al[m], bhv[n], acc[m][n], 0, 0, 0);
            }
        }
        __syncthreads();

        xq0 = xn0; xq1 = xn1; xq2 = xn2; xq3 = xn3;
    }

    #pragma unroll
    for (int n = 0; n < 4; n++) {
        int gd = wc * 64 + n * 16 + lr;
        #pragma unroll
        for (int m = 0; m < 4; m++) {
            int gq = q0 + wr * 64 + m * 16 + kb * 4;
            float* dst = outh + ((size_t)bh * QL + gq) * 128 + gd;
            f32x4 c = acc[m][n];
            dst[0 * 128] = c[0];
            dst[1 * 128] = c[1];
            dst[2 * 128] = c[2];
            dst[3 * 128] = c[3];
        }
    }
}

// ---------------------------------------------------------------------------
// Output projection via split-bf16 MFMA, 2-way split-K (validated round 14)
// ---------------------------------------------------------------------------
__global__ __launch_bounds__(256) void oproj_mfma_kernel(
    const float* __restrict__ outh, const float* __restrict__ Woa, const float* __restrict__ Wob,
    float* __restrict__ opart)
{
    int bt = blockIdx.x;                  // 64 = 4 b * 16 t-tiles
    int b = bt >> 4, tt = bt & 15;
    int t0 = tt * 128;
    int n0 = blockIdx.y * 128;
    int sel = blockIdx.z >> 1;
    int ks  = blockIdx.z & 1;
    const float* W = sel ? Wob : Woa;
    int doff = sel ? 64 : 0;

    __shared__ short lA[128 * 64];
    __shared__ short lB[128 * 64];

    int t = threadIdx.x;
    int srow = t >> 1, shalf = t & 1;
    int l = t & 63, w = t >> 6;
    int wr = w >> 1, wc = w & 1;
    int lr = l & 15, kb = l >> 4;

    f32x4 acc[4][4] = {};

    for (int kc = ks * 128; kc < ks * 128 + 128; kc += 32) {
        {
            int k0 = kc + shalf * 16;
            int h = k0 >> 6, d0 = k0 & 63;
            const float* srcA = outh + ((size_t)(b * NH + h) * QL + t0 + srow) * 128 + doff + d0;
            float xa[16];
            #pragma unroll
            for (int j = 0; j < 4; j++)
                *(float4*)&xa[j * 4] = *(const float4*)(srcA + j * 4);
            bf16x8 h0, l0, h1, l1;
            split8(&xa[0], h0, l0);
            split8(&xa[8], h1, l1);
            int base = srow * 64, r7 = srow & 7;
            *(bf16x8*)&lA[base + (((4 * shalf + 0) ^ r7) * 8)] = h0;
            *(bf16x8*)&lA[base + (((4 * shalf + 1) ^ r7) * 8)] = l0;
            *(bf16x8*)&lA[base + (((4 * shalf + 2) ^ r7) * 8)] = h1;
            *(bf16x8*)&lA[base + (((4 * shalf + 3) ^ r7) * 8)] = l1;
        }
        {
            int ncol = srow;
            float xb[16];
            #pragma unroll
            for (int j = 0; j < 16; j++)
                xb[j] = W[(size_t)(kc + shalf * 16 + j) * 256 + n0 + ncol];
            bf16x8 h0, l0, h1, l1;
            split8(&xb[0], h0, l0);
            split8(&xb[8], h1, l1);
            int base = ncol * 64, r7 = ncol & 7;
            *(bf16x8*)&lB[base + (((4 * shalf + 0) ^ r7) * 8)] = h0;
            *(bf16x8*)&lB[base + (((4 * shalf + 1) ^ r7) * 8)] = l0;
            *(bf16x8*)&lB[base + (((4 * shalf + 2) ^ r7) * 8)] = h1;
            *(bf16x8*)&lB[base + (((4 * shalf + 3) ^ r7) * 8)] = l1;
        }
        __syncthreads();

        bf16x8 ah[4], al[4], bhv[4], blv[4];
        #pragma unroll
        for (int m = 0; m < 4; m++) {
            int r = wr * 64 + m * 16 + lr;
            int r7 = r & 7, base = r * 64;
            ah[m] = *(bf16x8*)&lA[base + (((2 * kb + 0) ^ r7) * 8)];
            al[m] = *(bf16x8*)&lA[base + (((2 * kb + 1) ^ r7) * 8)];
        }
        #pragma unroll
        for (int n = 0; n < 4; n++) {
            int r = wc * 64 + n * 16 + lr;
            int r7 = r & 7, base = r * 64;
            bhv[n] = *(bf16x8*)&lB[base + (((2 * kb + 0) ^ r7) * 8)];
            blv[n] = *(bf16x8*)&lB[base + (((2 * kb + 1) ^ r7) * 8)];
        }
        #pragma unroll
        for (int m = 0; m < 4; m++) {
            #pragma unroll
            for (int n = 0; n < 4; n++) {
                acc[m][n] = __builtin_amdgcn_mfma_f32_16x16x32_bf16(ah[m], bhv[n], acc[m][n], 0, 0, 0);
                acc[m][n] = __builtin_amdgcn_mfma_f32_16x16x32_bf16(ah[m], blv[n], acc[m][n], 0, 0, 0);
                acc[m][n] = __builtin_amdgcn_mfma_f32_16x16x32_bf16(al[m], bhv[n], acc[m][n], 0, 0, 0);
            }
        }
        __syncthreads();
    }

    float* dstbase = opart + (size_t)ks * OSZ;
    #pragma unroll
    for (int n = 0; n < 4; n++) {
        int gcol = n0 + wc * 64 + n * 16 + lr;
        #pragma unroll
        for (int m = 0; m < 4; m++) {
            int grow = t0 + wr * 64 + m * 16 + kb * 4;
            float* dst = dstbase + ((size_t)((sel * BS + b) * QL) + grow) * 256 + gcol;
            f32x4 c = acc[m][n];
            dst[0 * 256] = c[0];
            dst[1 * 256] = c[1];
            dst[2 * 256] = c[2];
            dst[3 * 256] = c[3];
        }
    }
}

// ---------------------------------------------------------------------------
// Sum the 2 oproj split-K partials into the final output.
// ---------------------------------------------------------------------------
__global__ __launch_bounds__(256) void oadd_kernel(
    const float* __restrict__ opart, float* __restrict__ outp)
{
    size_t i = ((size_t)blockIdx.x * 256 + threadIdx.x) * 4;   // 4096 blocks cover OSZ
    float4 a = *(const float4*)(opart + i);
    float4 b = *(const float4*)(opart + OSZ + i);
    float4 o = make_float4(a.x + b.x, a.y + b.y, a.z + b.z, a.w + b.w);
    *(float4*)(outp + i) = o;
}

extern "C" void kernel_launch(void* const* d_in, const int* in_sizes, int n_in,
                              void* d_out, int out_size, void* d_ws, size_t ws_size,
                              hipStream_t stream)
{
    const float* q    = (const float*)d_in[0];
    const float* k    = (const float*)d_in[1];
    const float* v    = (const float*)d_in[2];
    const float* qse  = (const float*)d_in[3];
    const float* kvse = (const float*)d_in[4];
    const float* bias = (const float*)d_in[5];
    const int*   mask = (const int*)d_in[6];
    const float* Wqa  = (const float*)d_in[7];
    const float* Wqb  = (const float*)d_in[8];
    const float* Wka  = (const float*)d_in[9];
    const float* Wkb  = (const float*)d_in[10];
    const float* Wva  = (const float*)d_in[11];
    const float* Wvb  = (const float*)d_in[12];
    const float* Woa  = (const float*)d_in[13];
    const float* Wob  = (const float*)d_in[14];

    float* outp = (float*)d_out;
    float* attn = outp + OSZ;                  // attn region of d_out

    float* ws     = (float*)d_ws;
    float* qa     = ws + 0 * FSZ;
    float* qb     = ws + 1 * FSZ;
    float* ka     = ws + 2 * FSZ;
    float* kb     = ws + 3 * FSZ;
    float* va     = ws + 4 * FSZ;
    float* vb     = ws + 5 * FSZ;
    short* qrotS  = (short*)(ws + 6 * FSZ);    // 16.8 MB
    short* krotS  = (short*)(ws + 10 * FSZ);   // 16.8 MB
    float* stats  = ws + 14 * FSZ;             // 4 MB
    short* vT     = (short*)(ws + 16 * FSZ);   // 16.8 MB
    float* outh   = ws + 20 * FSZ;             // 16 MB
    float* opart  = ws + 24 * FSZ;             // 2 x OSZ = 33.6 MB

    proj_mfma_kernel<<<dim3(64, 6), 256, 0, stream>>>(q, k, v, Wqa, Wqb, Wka, Wkb, Wva, Wvb, ws);
    vtrans_kernel<<<dim3(64, 16), 256, 0, stream>>>(va, vb, vT);
    rot_split_kernel<<<dim3(QL, BS, 2), 256, 0, stream>>>(qa, qb, ka, kb, qse, kvse, qrotS, krotS);
    score_mfma_kernel<<<4096, 256, 0, stream>>>(qrotS, krotS, bias, mask, attn, stats);
    pv_fused_kernel<<<256, 256, 0, stream>>>(attn, vT, stats, outh);
    oproj_mfma_kernel<<<dim3(64, 2, 4), 256, 0, stream>>>(outh, Woa, Wob, opart);
    oadd_kernel<<<4096, 256, 0, stream>>>(opart, outp);
}

// Round 16
// 606.546 us; speedup vs baseline: 1.0581x; 1.0060x over previous
//
#include <hip/hip_runtime.h>
#include <math.h>

#define QL 2048
#define SL 2048
#define BS 4
#define NH 4
#define FSZ ((size_t)BS * QL * 128)   // 1,048,576 floats = 4 MB
#define OSZ ((size_t)2 * BS * QL * 256)  // 4,194,304 floats

typedef short bf16x8 __attribute__((ext_vector_type(8)));
typedef float f32x4 __attribute__((ext_vector_type(4)));

__device__ __forceinline__ short to_bf16_rne(float x) {
    unsigned u = __float_as_uint(x);
    unsigned r = u + 0x7fffu + ((u >> 16) & 1u);
    return (short)(r >> 16);
}

__device__ __forceinline__ void split8(const float* x, bf16x8& hi, bf16x8& lo) {
    #pragma unroll
    for (int j = 0; j < 8; j++) {
        short hh = to_bf16_rne(x[j]);
        float hf = __uint_as_float(((unsigned)(unsigned short)hh) << 16);
        hi[j] = hh;
        lo[j] = to_bf16_rne(x[j] - hf);
    }
}

// ---------------------------------------------------------------------------
// Projection GEMM via split-bf16 MFMA (validated round 10)
// ---------------------------------------------------------------------------
__global__ __launch_bounds__(256) void proj_mfma_kernel(
    const float* __restrict__ q, const float* __restrict__ k, const float* __restrict__ v,
    const float* __restrict__ Wqa, const float* __restrict__ Wqb,
    const float* __restrict__ Wka, const float* __restrict__ Wkb,
    const float* __restrict__ Wva, const float* __restrict__ Wvb,
    float* __restrict__ ws)
{
    int id = blockIdx.y;
    const float* X; const float* W;
    const size_t HALF = (size_t)BS * QL * 256;
    switch (id) {
      case 0: X = q;        W = Wqa; break;
      case 1: X = q + HALF; W = Wqb; break;
      case 2: X = k;        W = Wka; break;
      case 3: X = k + HALF; W = Wkb; break;
      case 4: X = v;        W = Wva; break;
      default:X = v + HALF; W = Wvb; break;
    }
    float* Y = ws + (size_t)id * FSZ;
    int m0 = blockIdx.x * 128;

    __shared__ short lA[128 * 64];
    __shared__ short lB[128 * 64];

    int t = threadIdx.x;
    int srow = t >> 1, shalf = t & 1;
    int l = t & 63, w = t >> 6;
    int wr = w >> 1, wc = w & 1;
    int lr = l & 15, kb = l >> 4;

    f32x4 acc[4][4] = {};

    for (int kc = 0; kc < 256; kc += 32) {
        {
            const float* srcA = X + (size_t)(m0 + srow) * 256 + kc + shalf * 16;
            float xa[16];
            #pragma unroll
            for (int j = 0; j < 4; j++)
                *(float4*)&xa[j * 4] = *(const float4*)(srcA + j * 4);
            bf16x8 h0, l0, h1, l1;
            split8(&xa[0], h0, l0);
            split8(&xa[8], h1, l1);
            int base = srow * 64, r7 = srow & 7;
            *(bf16x8*)&lA[base + (((4 * shalf + 0) ^ r7) * 8)] = h0;
            *(bf16x8*)&lA[base + (((4 * shalf + 1) ^ r7) * 8)] = l0;
            *(bf16x8*)&lA[base + (((4 * shalf + 2) ^ r7) * 8)] = h1;
            *(bf16x8*)&lA[base + (((4 * shalf + 3) ^ r7) * 8)] = l1;
        }
        {
            int ncol = srow;
            float xb[16];
            #pragma unroll
            for (int j = 0; j < 16; j++)
                xb[j] = W[(size_t)(kc + shalf * 16 + j) * 128 + ncol];
            bf16x8 h0, l0, h1, l1;
            split8(&xb[0], h0, l0);
            split8(&xb[8], h1, l1);
            int base = ncol * 64, r7 = ncol & 7;
            *(bf16x8*)&lB[base + (((4 * shalf + 0) ^ r7) * 8)] = h0;
            *(bf16x8*)&lB[base + (((4 * shalf + 1) ^ r7) * 8)] = l0;
            *(bf16x8*)&lB[base + (((4 * shalf + 2) ^ r7) * 8)] = h1;
            *(bf16x8*)&lB[base + (((4 * shalf + 3) ^ r7) * 8)] = l1;
        }
        __syncthreads();

        bf16x8 ah[4], al[4], bhv[4], blv[4];
        #pragma unroll
        for (int m = 0; m < 4; m++) {
            int r = wr * 64 + m * 16 + lr;
            int r7 = r & 7, base = r * 64;
            ah[m] = *(bf16x8*)&lA[base + (((2 * kb + 0) ^ r7) * 8)];
            al[m] = *(bf16x8*)&lA[base + (((2 * kb + 1) ^ r7) * 8)];
        }
        #pragma unroll
        for (int n = 0; n < 4; n++) {
            int r = wc * 64 + n * 16 + lr;
            int r7 = r & 7, base = r * 64;
            bhv[n] = *(bf16x8*)&lB[base + (((2 * kb + 0) ^ r7) * 8)];
            blv[n] = *(bf16x8*)&lB[base + (((2 * kb + 1) ^ r7) * 8)];
        }
        #pragma unroll
        for (int m = 0; m < 4; m++) {
            #pragma unroll
            for (int n = 0; n < 4; n++) {
                acc[m][n] = __builtin_amdgcn_mfma_f32_16x16x32_bf16(ah[m], bhv[n], acc[m][n], 0, 0, 0);
                acc[m][n] = __builtin_amdgcn_mfma_f32_16x16x32_bf16(ah[m], blv[n], acc[m][n], 0, 0, 0);
                acc[m][n] = __builtin_amdgcn_mfma_f32_16x16x32_bf16(al[m], bhv[n], acc[m][n], 0, 0, 0);
            }
        }
        __syncthreads();
    }

    #pragma unroll
    for (int n = 0; n < 4; n++) {
        int gcol = wc * 64 + n * 16 + lr;
        #pragma unroll
        for (int m = 0; m < 4; m++) {
            int grow = m0 + wr * 64 + m * 16 + kb * 4;
            float* dst = Y + (size_t)grow * 128 + gcol;
            f32x4 c = acc[m][n];
            dst[0 * 128] = c[0];
            dst[1 * 128] = c[1];
            dst[2 * 128] = c[2];
            dst[3 * 128] = c[3];
        }
    }
}

// ---------------------------------------------------------------------------
// Spatial rotation -> split-bf16 pre-swizzled planes; z selects q vs kv.
// ---------------------------------------------------------------------------
__global__ __launch_bounds__(256) void rot_split_kernel(
    const float* __restrict__ qa, const float* __restrict__ qb,
    const float* __restrict__ ka, const float* __restrict__ kb,
    const float* __restrict__ qse, const float* __restrict__ kvse,
    short* __restrict__ qrotS, short* __restrict__ krotS)
{
    int tkn = blockIdx.x;
    int b = blockIdx.y;
    int z = blockIdx.z;                       // 0 = q, 1 = kv
    const float* ha = z ? ka : qa;
    const float* hb = z ? kb : qb;
    const float* E = z ? (kvse + (size_t)(b * SL + tkn) * 16384)
                       : (qse + (size_t)b * 16384);
    short* rotS = z ? krotS : qrotS;

    __shared__ float hv[4][128];
    __shared__ float outl[4][128];
    int tid = threadIdx.x;
    size_t tok = (size_t)(b * QL + tkn) * 128;
    for (int idx = tid; idx < 512; idx += 256) {
        int h = idx >> 7, d = idx & 127;
        float val = (d < 64) ? ha[tok + (h & 1) * 64 + d]
                             : hb[tok + (h >> 1) * 64 + (d - 64)];
        hv[h][d] = val;
    }
    __syncthreads();
    int w = tid >> 6, lane = tid & 63;
    int half = lane >> 5, l5 = lane & 31;
    for (int it = 0; it < 16; ++it) {
        int i = w * 32 + it * 2 + half;
        float4 e = *(const float4*)(E + (size_t)i * 128 + l5 * 4);
        float acc[4];
        #pragma unroll
        for (int h = 0; h < 4; h++) {
            float4 x = *(const float4*)&hv[h][l5 * 4];
            acc[h] = e.x * x.x + e.y * x.y + e.z * x.z + e.w * x.w;
        }
        #pragma unroll
        for (int off = 1; off < 32; off <<= 1) {
            #pragma unroll
            for (int h = 0; h < 4; h++) acc[h] += __shfl_xor(acc[h], off);
        }
        if (l5 < 4) outl[l5][i] = acc[l5];
    }
    __syncthreads();
    if (tid < 128) {
        int h    = tid >> 5;
        int kcid = (tid >> 3) & 3;
        int s    = tid & 7;
        int shalf = s >> 2;
        int isLo  = s & 1;
        int jbase = ((s >> 1) & 1) * 8;
        int dbase = kcid * 32 + shalf * 16 + jbase;
        bf16x8 outv;
        #pragma unroll
        for (int j = 0; j < 8; j++) {
            float x = outl[h][dbase + j];
            short hh = to_bf16_rne(x);
            if (isLo) {
                float hf = __uint_as_float(((unsigned)(unsigned short)hh) << 16);
                outv[j] = to_bf16_rne(x - hf);
            } else {
                outv[j] = hh;
            }
        }
        int bh = b * NH + h;
        int row = tkn & 127;
        size_t base = ((((size_t)bh * 16 + (tkn >> 7)) * 4 + kcid) * 128 + row) * 64;
        *(bf16x8*)&rotS[base + (size_t)((s ^ (row & 7)) * 8)] = outv;
    }
}

// ---------------------------------------------------------------------------
// Score GEMM via split-bf16 MFMA + fused softmax partials.
// __launch_bounds__(256,3): force >=3 waves/EU (12 waves/CU) to hide the
// staging/S-store latency; regalloc capped ~168 VGPR.
// ---------------------------------------------------------------------------
__global__ __launch_bounds__(256, 3) void score_mfma_kernel(
    const short* __restrict__ qrotS, const short* __restrict__ krotS,
    const float* __restrict__ bias, const int* __restrict__ mask,
    float* __restrict__ attn, float* __restrict__ stats)
{
    __shared__ short lA[128 * 64];
    __shared__ short lB[128 * 64];
    __shared__ float redM[128][2];
    __shared__ float redS[128][2];

    int bid = blockIdx.x;                       // 4096
    int wg = (bid & 7) * 512 + (bid >> 3);      // XCD-chunked swizzle
    int bh = wg >> 8;
    int qt = (wg >> 4) & 15, st = wg & 15;
    int q0 = qt * 128, s0 = st * 128;
    int b = bh >> 2;

    int t = threadIdx.x;
    int l = t & 63, w = t >> 6;
    int wr = w >> 1, wc = w & 1;
    int lr = l & 15, kb = l >> 4;

    const short* Abase = qrotS + (((size_t)bh * 16 + qt) * 4) * 8192;
    const short* Bbase = krotS + (((size_t)bh * 16 + st) * 4) * 8192;

    f32x4 acc[4][4] = {};

    for (int kcid = 0; kcid < 4; kcid++) {
        {
            const bf16x8* srcA = (const bf16x8*)(Abase + (size_t)kcid * 8192) + t * 4;
            const bf16x8* srcB = (const bf16x8*)(Bbase + (size_t)kcid * 8192) + t * 4;
            bf16x8 a0 = srcA[0], a1 = srcA[1], a2 = srcA[2], a3 = srcA[3];
            bf16x8 b0 = srcB[0], b1 = srcB[1], b2 = srcB[2], b3 = srcB[3];
            bf16x8* dA = (bf16x8*)lA + t * 4;
            bf16x8* dB = (bf16x8*)lB + t * 4;
            dA[0] = a0; dA[1] = a1; dA[2] = a2; dA[3] = a3;
            dB[0] = b0; dB[1] = b1; dB[2] = b2; dB[3] = b3;
        }
        __syncthreads();

        bf16x8 ah[4], al[4], bhv[4], blv[4];
        #pragma unroll
        for (int m = 0; m < 4; m++) {
            int r = wr * 64 + m * 16 + lr;
            int r7 = r & 7, base = r * 64;
            ah[m] = *(bf16x8*)&lA[base + (((2 * kb + 0) ^ r7) * 8)];
            al[m] = *(bf16x8*)&lA[base + (((2 * kb + 1) ^ r7) * 8)];
        }
        #pragma unroll
        for (int n = 0; n < 4; n++) {
            int r = wc * 64 + n * 16 + lr;
            int r7 = r & 7, base = r * 64;
            bhv[n] = *(bf16x8*)&lB[base + (((2 * kb + 0) ^ r7) * 8)];
            blv[n] = *(bf16x8*)&lB[base + (((2 * kb + 1) ^ r7) * 8)];
        }
        #pragma unroll
        for (int m = 0; m < 4; m++) {
            #pragma unroll
            for (int n = 0; n < 4; n++) {
                acc[m][n] = __builtin_amdgcn_mfma_f32_16x16x32_bf16(ah[m], bhv[n], acc[m][n], 0, 0, 0);
                acc[m][n] = __builtin_amdgcn_mfma_f32_16x16x32_bf16(ah[m], blv[n], acc[m][n], 0, 0, 0);
                acc[m][n] = __builtin_amdgcn_mfma_f32_16x16x32_bf16(al[m], bhv[n], acc[m][n], 0, 0, 0);
            }
        }
        __syncthreads();
    }

    // ---- epilogue: finalize S in registers, write raw S ----
    const float scale = 0.08838834764831845f;   // 1/sqrt(128)
    #pragma unroll
    for (int n = 0; n < 4; n++) {
        int gs = s0 + wc * 64 + n * 16 + lr;
        float adj = -1e9f * (float)mask[b * SL + gs] - bias[b * SL + gs];
        #pragma unroll
        for (int m = 0; m < 4; m++) {
            int gq = q0 + wr * 64 + m * 16 + kb * 4;
            float* dst = attn + ((size_t)bh * QL + gq) * SL + gs;
            f32x4 c = acc[m][n];
            c[0] = c[0] * scale + adj;
            c[1] = c[1] * scale + adj;
            c[2] = c[2] * scale + adj;
            c[3] = c[3] * scale + adj;
            acc[m][n] = c;
            dst[0 * SL] = c[0];
            dst[1 * SL] = c[1];
            dst[2 * SL] = c[2];
            dst[3 * SL] = c[3];
        }
    }

    // ---- per-row tile max ----
    #pragma unroll
    for (int m = 0; m < 4; m++) {
        #pragma unroll
        for (int i = 0; i < 4; i++) {
            float rm = fmaxf(fmaxf(acc[m][0][i], acc[m][1][i]),
                             fmaxf(acc[m][2][i], acc[m][3][i]));
            rm = fmaxf(rm, __shfl_xor(rm, 1));
            rm = fmaxf(rm, __shfl_xor(rm, 2));
            rm = fmaxf(rm, __shfl_xor(rm, 4));
            rm = fmaxf(rm, __shfl_xor(rm, 8));
            if (lr == 0) redM[wr * 64 + m * 16 + kb * 4 + i][wc] = rm;
        }
    }
    __syncthreads();
    // ---- per-row tile expsum relative to combined tile max ----
    #pragma unroll
    for (int m = 0; m < 4; m++) {
        #pragma unroll
        for (int i = 0; i < 4; i++) {
            int row = wr * 64 + m * 16 + kb * 4 + i;
            float mt = fmaxf(redM[row][0], redM[row][1]);
            float es = __expf(acc[m][0][i] - mt) + __expf(acc[m][1][i] - mt)
                     + __expf(acc[m][2][i] - mt) + __expf(acc[m][3][i] - mt);
            es += __shfl_xor(es, 1);
            es += __shfl_xor(es, 2);
            es += __shfl_xor(es, 4);
            es += __shfl_xor(es, 8);
            if (lr == 0) redS[row][wc] = es;
        }
    }
    __syncthreads();
    if (t < 128) {
        float mt = fmaxf(redM[t][0], redM[t][1]);
        float es = redS[t][0] + redS[t][1];
        size_t r = (size_t)bh * QL + q0 + t;
        stats[(r * 16 + st) * 2 + 0] = mt;
        stats[(r * 16 + st) * 2 + 1] = es;
    }
}

// ---------------------------------------------------------------------------
// V pre-transpose (unchanged, validated round 5)
// ---------------------------------------------------------------------------
__global__ __launch_bounds__(256) void vtrans_kernel(
    const float* __restrict__ va, const float* __restrict__ vb,
    short* __restrict__ vT)
{
    int sblk = blockIdx.x;                    // 64
    int bh = blockIdx.y;                      // 16
    int b = bh >> 2, h = bh & 3;
    int hao = (h & 1) * 64, hbo = (h >> 1) * 64;
    __shared__ float vt[32][132];
    int t = threadIdx.x;
    for (int f = t; f < 1024; f += 256) {
        int s = f >> 5, c4 = (f & 31) * 4;
        size_t tok = (size_t)(b * SL + sblk * 32 + s) * 128;
        float4 vv = (c4 < 64) ? *(const float4*)(va + tok + hao + c4)
                              : *(const float4*)(vb + tok + hbo + (c4 - 64));
        *(float4*)&vt[s][c4] = vv;
    }
    __syncthreads();
    int d = t >> 1, shalf = t & 1;
    bf16x8 hi[2], lo[2];
    #pragma unroll
    for (int kb2 = 0; kb2 < 2; kb2++) {
        int kb = shalf * 2 + kb2;
        #pragma unroll
        for (int j = 0; j < 8; j++) {
            float x = vt[kb * 8 + j][d];
            short hh = to_bf16_rne(x);
            float hf = __uint_as_float(((unsigned)(unsigned short)hh) << 16);
            hi[kb2][j] = hh;
            lo[kb2][j] = to_bf16_rne(x - hf);
        }
    }
    size_t base = (((size_t)bh * 64 + sblk) * 128 + d) * 64;
    int d7 = d & 7;
    *(bf16x8*)&vT[base + (size_t)(((2 * (shalf * 2 + 0) + 0) ^ d7) * 8)] = hi[0];
    *(bf16x8*)&vT[base + (size_t)(((2 * (shalf * 2 + 0) + 1) ^ d7) * 8)] = lo[0];
    *(bf16x8*)&vT[base + (size_t)(((2 * (shalf * 2 + 1) + 0) ^ d7) * 8)] = hi[1];
    *(bf16x8*)&vT[base + (size_t)(((2 * (shalf * 2 + 1) + 1) ^ d7) * 8)] = lo[1];
}

// ---------------------------------------------------------------------------
// Fused softmax+PV with in-kernel stats combine and S-load register
// double-buffering (validated round 15).
// ---------------------------------------------------------------------------
__global__ __launch_bounds__(256) void pv_fused_kernel(
    float* __restrict__ attn, const short* __restrict__ vT,
    const float* __restrict__ stats,
    float* __restrict__ outh)
{
    __shared__ short lA[128 * 64];
    __shared__ short lB[128 * 64];
    __shared__ float lrm[128];
    __shared__ float lriv[128];

    int bid = blockIdx.x;                     // 256
    int wg = (bid & 7) * 32 + (bid >> 3);     // XCD swizzle
    int bh = wg >> 4, qt = wg & 15;
    int q0 = qt * 128;

    float* Ag = attn + ((size_t)bh * QL + q0) * SL;
    const short* Bg = vT + (size_t)bh * 64 * 8192;

    int t = threadIdx.x;
    int srow = t >> 1, shalf = t & 1;
    int l = t & 63, w = t >> 6;
    int wr = w >> 1, wc = w & 1;
    int lr = l & 15, kb = l >> 4;

    if (t < 128) {
        const float* src = stats + ((size_t)bh * QL + q0 + t) * 32;
        float4 p[8];
        #pragma unroll
        for (int j = 0; j < 8; j++) p[j] = *(const float4*)(src + j * 4);
        float m = -INFINITY;
        #pragma unroll
        for (int j = 0; j < 8; j++) { m = fmaxf(m, p[j].x); m = fmaxf(m, p[j].z); }
        float s = 0.f;
        #pragma unroll
        for (int j = 0; j < 8; j++) {
            s += p[j].y * __expf(p[j].x - m);
            s += p[j].w * __expf(p[j].z - m);
        }
        lrm[t] = m;
        lriv[t] = 1.0f / s;
    }
    __syncthreads();
    float rm  = lrm[srow];
    float riv = lriv[srow];

    f32x4 acc[4][4] = {};

    float4 xq0, xq1, xq2, xq3;
    {
        const float* src = Ag + (size_t)srow * SL + 0 + shalf * 16;
        xq0 = *(const float4*)(src + 0);
        xq1 = *(const float4*)(src + 4);
        xq2 = *(const float4*)(src + 8);
        xq3 = *(const float4*)(src + 12);
    }

    for (int sblk = 0; sblk < 64; sblk++) {
        float4 xn0, xn1, xn2, xn3;
        if (sblk < 63) {
            const float* srcn = Ag + (size_t)srow * SL + (sblk + 1) * 32 + shalf * 16;
            xn0 = *(const float4*)(srcn + 0);
            xn1 = *(const float4*)(srcn + 4);
            xn2 = *(const float4*)(srcn + 8);
            xn3 = *(const float4*)(srcn + 12);
        }
        {
            float x[16];
            *(float4*)&x[0]  = xq0;
            *(float4*)&x[4]  = xq1;
            *(float4*)&x[8]  = xq2;
            *(float4*)&x[12] = xq3;
            #pragma unroll
            for (int j = 0; j < 16; j++)
                x[j] = __expf(x[j] - rm) * riv;
            float* src = Ag + (size_t)srow * SL + sblk * 32 + shalf * 16;
            #pragma unroll
            for (int j = 0; j < 4; j++)
                *(float4*)(src + j * 4) = *(float4*)&x[j * 4];
            bf16x8 h0, l0, h1, l1;
            split8(&x[0], h0, l0);
            split8(&x[8], h1, l1);
            int base = srow * 64, r7 = srow & 7;
            *(bf16x8*)&lA[base + (((4 * shalf + 0) ^ r7) * 8)] = h0;
            *(bf16x8*)&lA[base + (((4 * shalf + 1) ^ r7) * 8)] = l0;
            *(bf16x8*)&lA[base + (((4 * shalf + 2) ^ r7) * 8)] = h1;
            *(bf16x8*)&lA[base + (((4 * shalf + 3) ^ r7) * 8)] = l1;
        }
        {
            const bf16x8* src = (const bf16x8*)(Bg + (size_t)sblk * 8192) + t * 4;
            bf16x8 v0 = src[0], v1 = src[1], v2 = src[2], v3 = src[3];
            bf16x8* dst = (bf16x8*)lB + t * 4;
            dst[0] = v0; dst[1] = v1; dst[2] = v2; dst[3] = v3;
        }
        __syncthreads();

        bf16x8 ah[4], al[4], bhv[4], blv[4];
        #pragma unroll
        for (int m = 0; m < 4; m++) {
            int r = wr * 64 + m * 16 + lr;
            int r7 = r & 7, base = r * 64;
            ah[m] = *(bf16x8*)&lA[base + (((2 * kb + 0) ^ r7) * 8)];
            al[m] = *(bf16x8*)&lA[base + (((2 * kb + 1) ^ r7) * 8)];
        }
        #pragma unroll
        for (int n = 0; n < 4; n++) {
            int r = wc * 64 + n * 16 + lr;
            int r7 = r & 7, base = r * 64;
            bhv[n] = *(bf16x8*)&lB[base + (((2 * kb + 0) ^ r7) * 8)];
            blv[n] = *(bf16x8*)&lB[base + (((2 * kb + 1) ^ r7) * 8)];
        }
        #pragma unroll
        for (int m = 0; m < 4; m++) {
            #pragma unroll
            for (int n = 0; n < 4; n++) {
                acc[m][n] = __builtin_amdgcn_mfma_f32_16x16x32_bf16(ah[m], bhv[n], acc[m][n], 0, 0, 0);
                acc[m][n] = __builtin_amdgcn_mfma_f32_16x16x32_bf16(ah[m], blv[n], acc[m][n], 0, 0, 0);
                acc[m][n] = __builtin_amdgcn_mfma_f32_16x16x32_bf16(al[m], bhv[n], acc[m][n], 0, 0, 0);
            }
        }
        __syncthreads();

        xq0 = xn0; xq1 = xn1; xq2 = xn2; xq3 = xn3;
    }

    #pragma unroll
    for (int n = 0; n < 4; n++) {
        int gd = wc * 64 + n * 16 + lr;
        #pragma unroll
        for (int m = 0; m < 4; m++) {
            int gq = q0 + wr * 64 + m * 16 + kb * 4;
            float* dst = outh + ((size_t)bh * QL + gq) * 128 + gd;
            f32x4 c = acc[m][n];
            dst[0 * 128] = c[0];
            dst[1 * 128] = c[1];
            dst[2 * 128] = c[2];
            dst[3 * 128] = c[3];
        }
    }
}

// ---------------------------------------------------------------------------
// Output projection via split-bf16 MFMA, 2-way split-K (validated round 14)
// ---------------------------------------------------------------------------
__global__ __launch_bounds__(256) void oproj_mfma_kernel(
    const float* __restrict__ outh, const float* __restrict__ Woa, const float* __restrict__ Wob,
    float* __restrict__ opart)
{
    int bt = blockIdx.x;                  // 64 = 4 b * 16 t-tiles
    int b = bt >> 4, tt = bt & 15;
    int t0 = tt * 128;
    int n0 = blockIdx.y * 128;
    int sel = blockIdx.z >> 1;
    int ks  = blockIdx.z & 1;
    const float* W = sel ? Wob : Woa;
    int doff = sel ? 64 : 0;

    __shared__ short lA[128 * 64];
    __shared__ short lB[128 * 64];

    int t = threadIdx.x;
    int srow = t >> 1, shalf = t & 1;
    int l = t & 63, w = t >> 6;
    int wr = w >> 1, wc = w & 1;
    int lr = l & 15, kb = l >> 4;

    f32x4 acc[4][4] = {};

    for (int kc = ks * 128; kc < ks * 128 + 128; kc += 32) {
        {
            int k0 = kc + shalf * 16;
            int h = k0 >> 6, d0 = k0 & 63;
            const float* srcA = outh + ((size_t)(b * NH + h) * QL + t0 + srow) * 128 + doff + d0;
            float xa[16];
            #pragma unroll
            for (int j = 0; j < 4; j++)
                *(float4*)&xa[j * 4] = *(const float4*)(srcA + j * 4);
            bf16x8 h0, l0, h1, l1;
            split8(&xa[0], h0, l0);
            split8(&xa[8], h1, l1);
            int base = srow * 64, r7 = srow & 7;
            *(bf16x8*)&lA[base + (((4 * shalf + 0) ^ r7) * 8)] = h0;
            *(bf16x8*)&lA[base + (((4 * shalf + 1) ^ r7) * 8)] = l0;
            *(bf16x8*)&lA[base + (((4 * shalf + 2) ^ r7) * 8)] = h1;
            *(bf16x8*)&lA[base + (((4 * shalf + 3) ^ r7) * 8)] = l1;
        }
        {
            int ncol = srow;
            float xb[16];
            #pragma unroll
            for (int j = 0; j < 16; j++)
                xb[j] = W[(size_t)(kc + shalf * 16 + j) * 256 + n0 + ncol];
            bf16x8 h0, l0, h1, l1;
            split8(&xb[0], h0, l0);
            split8(&xb[8], h1, l1);
            int base = ncol * 64, r7 = ncol & 7;
            *(bf16x8*)&lB[base + (((4 * shalf + 0) ^ r7) * 8)] = h0;
            *(bf16x8*)&lB[base + (((4 * shalf + 1) ^ r7) * 8)] = l0;
            *(bf16x8*)&lB[base + (((4 * shalf + 2) ^ r7) * 8)] = h1;
            *(bf16x8*)&lB[base + (((4 * shalf + 3) ^ r7) * 8)] = l1;
        }
        __syncthreads();

        bf16x8 ah[4], al[4], bhv[4], blv[4];
        #pragma unroll
        for (int m = 0; m < 4; m++) {
            int r = wr * 64 + m * 16 + lr;
            int r7 = r & 7, base = r * 64;
            ah[m] = *(bf16x8*)&lA[base + (((2 * kb + 0) ^ r7) * 8)];
            al[m] = *(bf16x8*)&lA[base + (((2 * kb + 1) ^ r7) * 8)];
        }
        #pragma unroll
        for (int n = 0; n < 4; n++) {
            int r = wc * 64 + n * 16 + lr;
            int r7 = r & 7, base = r * 64;
            bhv[n] = *(bf16x8*)&lB[base + (((2 * kb + 0) ^ r7) * 8)];
            blv[n] = *(bf16x8*)&lB[base + (((2 * kb + 1) ^ r7) * 8)];
        }
        #pragma unroll
        for (int m = 0; m < 4; m++) {
            #pragma unroll
            for (int n = 0; n < 4; n++) {
                acc[m][n] = __builtin_amdgcn_mfma_f32_16x16x32_bf16(ah[m], bhv[n], acc[m][n], 0, 0, 0);
                acc[m][n] = __builtin_amdgcn_mfma_f32_16x16x32_bf16(ah[m], blv[n], acc[m][n], 0, 0, 0);
                acc[m][n] = __builtin_amdgcn_mfma_f32_16x16x32_bf16(al[m], bhv[n], acc[m][n], 0, 0, 0);
            }
        }
        __syncthreads();
    }

    float* dstbase = opart + (size_t)ks * OSZ;
    #pragma unroll
    for (int n = 0; n < 4; n++) {
        int gcol = n0 + wc * 64 + n * 16 + lr;
        #pragma unroll
        for (int m = 0; m < 4; m++) {
            int grow = t0 + wr * 64 + m * 16 + kb * 4;
            float* dst = dstbase + ((size_t)((sel * BS + b) * QL) + grow) * 256 + gcol;
            f32x4 c = acc[m][n];
            dst[0 * 256] = c[0];
            dst[1 * 256] = c[1];
            dst[2 * 256] = c[2];
            dst[3 * 256] = c[3];
        }
    }
}

// ---------------------------------------------------------------------------
// Sum the 2 oproj split-K partials into the final output.
// ---------------------------------------------------------------------------
__global__ __launch_bounds__(256) void oadd_kernel(
    const float* __restrict__ opart, float* __restrict__ outp)
{
    size_t i = ((size_t)blockIdx.x * 256 + threadIdx.x) * 4;   // 4096 blocks cover OSZ
    float4 a = *(const float4*)(opart + i);
    float4 b = *(const float4*)(opart + OSZ + i);
    float4 o = make_float4(a.x + b.x, a.y + b.y, a.z + b.z, a.w + b.w);
    *(float4*)(outp + i) = o;
}

extern "C" void kernel_launch(void* const* d_in, const int* in_sizes, int n_in,
                              void* d_out, int out_size, void* d_ws, size_t ws_size,
                              hipStream_t stream)
{
    const float* q    = (const float*)d_in[0];
    const float* k    = (const float*)d_in[1];
    const float* v    = (const float*)d_in[2];
    const float* qse  = (const float*)d_in[3];
    const float* kvse = (const float*)d_in[4];
    const float* bias = (const float*)d_in[5];
    const int*   mask = (const int*)d_in[6];
    const float* Wqa  = (const float*)d_in[7];
    const float* Wqb  = (const float*)d_in[8];
    const float* Wka  = (const float*)d_in[9];
    const float* Wkb  = (const float*)d_in[10];
    const float* Wva  = (const float*)d_in[11];
    const float* Wvb  = (const float*)d_in[12];
    const float* Woa  = (const float*)d_in[13];
    const float* Wob  = (const float*)d_in[14];

    float* outp = (float*)d_out;
    float* attn = outp + OSZ;                  // attn region of d_out

    float* ws     = (float*)d_ws;
    float* qa     = ws + 0 * FSZ;
    float* qb     = ws + 1 * FSZ;
    float* ka     = ws + 2 * FSZ;
    float* kb     = ws + 3 * FSZ;
    float* va     = ws + 4 * FSZ;
    float* vb     = ws + 5 * FSZ;
    short* qrotS  = (short*)(ws + 6 * FSZ);    // 16.8 MB
    short* krotS  = (short*)(ws + 10 * FSZ);   // 16.8 MB
    float* stats  = ws + 14 * FSZ;             // 4 MB
    short* vT     = (short*)(ws + 16 * FSZ);   // 16.8 MB
    float* outh   = ws + 20 * FSZ;             // 16 MB
    float* opart  = ws + 24 * FSZ;             // 2 x OSZ = 33.6 MB

    proj_mfma_kernel<<<dim3(64, 6), 256, 0, stream>>>(q, k, v, Wqa, Wqb, Wka, Wkb, Wva, Wvb, ws);
    vtrans_kernel<<<dim3(64, 16), 256, 0, stream>>>(va, vb, vT);
    rot_split_kernel<<<dim3(QL, BS, 2), 256, 0, stream>>>(qa, qb, ka, kb, qse, kvse, qrotS, krotS);
    score_mfma_kernel<<<4096, 256, 0, stream>>>(qrotS, krotS, bias, mask, attn, stats);
    pv_fused_kernel<<<256, 256, 0, stream>>>(attn, vT, stats, outh);
    oproj_mfma_kernel<<<dim3(64, 2, 4), 256, 0, stream>>>(outh, Woa, Wob, opart);
    oadd_kernel<<<4096, 256, 0, stream>>>(opart, outp);
}